// Round 1
// baseline (2146.179 us; speedup 1.0000x reference)
//
#include <hip/hip_runtime.h>
#include <hip/hip_bf16.h>
#include <math.h>

#define NNODES 100000
#define NEDGES 500000

// ---------------- Layer 0 projection: proj0 = x @ W0^T, plus per-head scores ----
// Block: 256 threads, 32 nodes per block. Thread t holds W0 row t (64 regs).
__global__ __launch_bounds__(256) void k_proj0(
    const float* __restrict__ x, const float* __restrict__ W0,
    const float* __restrict__ a1, const float* __restrict__ a2,
    const float* __restrict__ a3,
    float* __restrict__ proj0, float* __restrict__ s1,
    float* __restrict__ s2, float* __restrict__ s3) {
  __shared__ float xs[32 * 64];
  const int t = threadIdx.x;
  const int base = blockIdx.x * 32;
  float w[64];
#pragma unroll
  for (int q = 0; q < 16; ++q) {
    float4 v = ((const float4*)W0)[t * 16 + q];
    w[q * 4 + 0] = v.x; w[q * 4 + 1] = v.y; w[q * 4 + 2] = v.z; w[q * 4 + 3] = v.w;
  }
  const float a1v = a1[t], a2v = a2[t], a3v = a3[t];
  for (int idx = t; idx < 32 * 64; idx += 256) xs[idx] = x[base * 64 + idx];
  __syncthreads();
  const int lane = t & 63, head = t >> 6;
  for (int i = 0; i < 32; ++i) {
    float acc = 0.f;
#pragma unroll
    for (int k = 0; k < 64; ++k) acc = fmaf(xs[i * 64 + k], w[k], acc);
    const int node = base + i;
    proj0[(size_t)node * 256 + t] = acc;
    float v1 = acc * a1v, v2 = acc * a2v, v3 = acc * a3v;
#pragma unroll
    for (int off = 32; off > 0; off >>= 1) {
      v1 += __shfl_xor(v1, off, 64);
      v2 += __shfl_xor(v2, off, 64);
      v3 += __shfl_xor(v3, off, 64);
    }
    if (lane == 0) {
      s1[node * 4 + head] = v1;
      s2[node * 4 + head] = v2;
      s3[node * 4 + head] = v3;
    }
  }
}

// ---------------- out0 init: out0[n, h*64+f] = x[n,f] + b0[h*64+f] -------------
__global__ void k_init_out0(const float* __restrict__ x, const float* __restrict__ b0,
                            float* __restrict__ out0) {
  const int idx = blockIdx.x * 256 + threadIdx.x;  // < N*256 exactly
  const int n = idx >> 8, c = idx & 255, f = c & 63;
  out0[idx] = x[(n << 6) + f] + b0[c];
}

// ---------------- Layer 0 edge pass A: e = exp(lrelu(score)); sums scatter -----
__global__ void k_edge_a0(const int* __restrict__ ei, const float* __restrict__ s1,
                          const float* __restrict__ s2, const float* __restrict__ s3,
                          float* __restrict__ ebuf, float* __restrict__ sums) {
  const int e = blockIdx.x * 256 + threadIdx.x;
  if (e >= NEDGES) return;
  const int drug = ei[e], tgt = ei[NEDGES + e], dis = ei[2 * NEDGES + e];
  const float4 sd = ((const float4*)s1)[drug];
  const float4 st = ((const float4*)s2)[tgt];
  const float4 sx = ((const float4*)s3)[dis];
  float sc[4] = {sd.x + st.x + sx.x, sd.y + st.y + sx.y,
                 sd.z + st.z + sx.z, sd.w + st.w + sx.w};
  float ee[4];
#pragma unroll
  for (int h = 0; h < 4; ++h) {
    float s = sc[h];
    s = s > 0.f ? s : 0.2f * s;
    ee[h] = __expf(s);
    atomicAdd(&sums[tgt * 4 + h], ee[h]);
    atomicAdd(&sums[dis * 4 + h], ee[h]);
  }
  ((float4*)ebuf)[e] = make_float4(ee[0], ee[1], ee[2], ee[3]);
}

// ---------------- Layer 0 edge pass B: scatter att-weighted messages -----------
// Block = 256 threads, 4 edges per block (looped). thread t -> (head=t/64, f=t%64)
__global__ __launch_bounds__(256) void k_edge_b0(
    const int* __restrict__ ei, const float* __restrict__ ebuf,
    const float* __restrict__ sums, const float* __restrict__ proj0,
    float* __restrict__ out0) {
  const int t = threadIdx.x;
  const int h = t >> 6;
  for (int i = 0; i < 4; ++i) {
    const int e = blockIdx.x * 4 + i;
    const int drug = ei[e], tgt = ei[NEDGES + e], dis = ei[2 * NEDGES + e];
    const float ee = ebuf[e * 4 + h];
    const float denom = sums[tgt * 4 + h] + sums[dis * 4 + h] + 1e-16f;
    const float att = ee / denom;
    const float v = proj0[(size_t)drug * 256 + t] * att;
    atomicAdd(&out0[(size_t)tgt * 256 + t], v);
    atomicAdd(&out0[(size_t)dis * 256 + t], v);
  }
}

// ---------------- elu in place over out0 --------------------------------------
__global__ void k_elu(float* __restrict__ out0) {
  const int idx = blockIdx.x * 256 + threadIdx.x;  // < N*256 exactly
  const float v = out0[idx];
  out0[idx] = v > 0.f ? v : expm1f(v);
}

// ---------------- Layer 1 GEMM: out[n,of] = sum_k h[n,k] * W[of,k] ------------
// W staged in LDS transposed [k][of] (conflict-free reads: 2 lanes/bank).
// h row read via wave-broadcast float4 global loads (L1-resident).
// DO_S=true: write proj1 + s-scores; else: write acc + b1 (skip path).
template <bool DO_S>
__global__ __launch_bounds__(256) void k_gemm1(
    const float* __restrict__ h, const float* __restrict__ W,
    const float* __restrict__ a1, const float* __restrict__ a2,
    const float* __restrict__ a3, const float* __restrict__ b1,
    float* __restrict__ outv, float* __restrict__ s1, float* __restrict__ s2,
    float* __restrict__ s3) {
  __shared__ float wlds[256 * 64];  // [k][of]
  const int t = threadIdx.x;
  for (int idx = t; idx < 256 * 64; idx += 256) {
    const int k = idx >> 6, of = idx & 63;
    wlds[idx] = W[of * 256 + k];
  }
  __syncthreads();
  const int lane = t & 63, wid = t >> 6;
  const int gw = blockIdx.x * 4 + wid, nw = gridDim.x * 4;
  float a1v = 0.f, a2v = 0.f, a3v = 0.f, b1v = 0.f;
  if (DO_S) { a1v = a1[lane]; a2v = a2[lane]; a3v = a3[lane]; }
  else { b1v = b1[lane]; }
  for (int node = gw; node < NNODES; node += nw) {
    const float4* hrow = (const float4*)(h + (size_t)node * 256);
    float acc = 0.f;
#pragma unroll 4
    for (int kq = 0; kq < 64; ++kq) {
      const float4 hv = hrow[kq];  // wave-uniform broadcast load
      const int kb = kq * 4;
      acc = fmaf(hv.x, wlds[(kb + 0) * 64 + lane], acc);
      acc = fmaf(hv.y, wlds[(kb + 1) * 64 + lane], acc);
      acc = fmaf(hv.z, wlds[(kb + 2) * 64 + lane], acc);
      acc = fmaf(hv.w, wlds[(kb + 3) * 64 + lane], acc);
    }
    if (DO_S) {
      outv[(size_t)node * 64 + lane] = acc;
      float v1 = acc * a1v, v2 = acc * a2v, v3 = acc * a3v;
#pragma unroll
      for (int off = 32; off > 0; off >>= 1) {
        v1 += __shfl_xor(v1, off, 64);
        v2 += __shfl_xor(v2, off, 64);
        v3 += __shfl_xor(v3, off, 64);
      }
      if (lane == 0) { s1[node] = v1; s2[node] = v2; s3[node] = v3; }
    } else {
      outv[(size_t)node * 64 + lane] = acc + b1v;
    }
  }
}

// ---------------- Layer 1 edge pass A -----------------------------------------
__global__ void k_edge_a1(const int* __restrict__ ei, const float* __restrict__ s1,
                          const float* __restrict__ s2, const float* __restrict__ s3,
                          float* __restrict__ ebuf, float* __restrict__ sums) {
  const int e = blockIdx.x * 256 + threadIdx.x;
  if (e >= NEDGES) return;
  const int drug = ei[e], tgt = ei[NEDGES + e], dis = ei[2 * NEDGES + e];
  float s = s1[drug] + s2[tgt] + s3[dis];
  s = s > 0.f ? s : 0.2f * s;
  const float ee = __expf(s);
  ebuf[e] = ee;
  atomicAdd(&sums[tgt], ee);
  atomicAdd(&sums[dis], ee);
}

// ---------------- Layer 1 edge pass B: wave per edge --------------------------
__global__ __launch_bounds__(256) void k_edge_b1(
    const int* __restrict__ ei, const float* __restrict__ ebuf,
    const float* __restrict__ sums, const float* __restrict__ proj1,
    float* __restrict__ dout) {
  const int lane = threadIdx.x & 63, wid = threadIdx.x >> 6;
  const int e = blockIdx.x * 4 + wid;
  if (e >= NEDGES) return;
  const int drug = ei[e], tgt = ei[NEDGES + e], dis = ei[2 * NEDGES + e];
  const float att = ebuf[e] / (sums[tgt] + sums[dis] + 1e-16f);
  const float v = proj1[(size_t)drug * 64 + lane] * att;
  atomicAdd(&dout[(size_t)tgt * 64 + lane], v);
  atomicAdd(&dout[(size_t)dis * 64 + lane], v);
}

extern "C" void kernel_launch(void* const* d_in, const int* in_sizes, int n_in,
                              void* d_out, int out_size, void* d_ws, size_t ws_size,
                              hipStream_t stream) {
  const float* x = (const float*)d_in[0];
  const int* ei = (const int*)d_in[1];
  const float* W0 = (const float*)d_in[2];
  const float* a10 = (const float*)d_in[3];
  const float* a20 = (const float*)d_in[4];
  const float* a30 = (const float*)d_in[5];
  // d_in[6] = Wskip0: unused (layer-0 skip is identity since F==DIN)
  const float* b0 = (const float*)d_in[7];
  const float* W1 = (const float*)d_in[8];
  const float* a11 = (const float*)d_in[9];
  const float* a21 = (const float*)d_in[10];
  const float* a31 = (const float*)d_in[11];
  const float* Wskip1 = (const float*)d_in[12];
  const float* b1 = (const float*)d_in[13];
  float* out = (float*)d_out;

  // Workspace layout (fp32). Layer-1 buffers alias the proj0 region (dead
  // after k_edge_b0). Total: 54.8M floats = 219.2 MB.
  float* R0 = (float*)d_ws;                                // N*256
  float* out0 = R0 + (size_t)NNODES * 256;                 // N*256
  float* s1_0 = out0 + (size_t)NNODES * 256;               // N*4 x3
  float* s2_0 = s1_0 + (size_t)NNODES * 4;
  float* s3_0 = s2_0 + (size_t)NNODES * 4;
  float* sums0 = s3_0 + (size_t)NNODES * 4;                // N*4
  float* ebuf0 = sums0 + (size_t)NNODES * 4;               // E*4
  float* proj0 = R0;
  // layer-1 aliases (written only after k_edge_b0):
  float* proj1 = R0;                                       // N*64
  float* s1_1 = R0 + (size_t)NNODES * 64;                  // N x3
  float* s2_1 = s1_1 + NNODES;
  float* s3_1 = s2_1 + NNODES;
  float* sums1 = s3_1 + NNODES;                            // N
  float* ebuf1 = sums1 + NNODES;                           // E

  hipMemsetAsync(sums0, 0, (size_t)NNODES * 4 * sizeof(float), stream);
  k_proj0<<<NNODES / 32, 256, 0, stream>>>(x, W0, a10, a20, a30, proj0, s1_0,
                                           s2_0, s3_0);
  k_init_out0<<<NNODES, 256, 0, stream>>>(x, b0, out0);
  k_edge_a0<<<(NEDGES + 255) / 256, 256, 0, stream>>>(ei, s1_0, s2_0, s3_0,
                                                      ebuf0, sums0);
  k_edge_b0<<<NEDGES / 4, 256, 0, stream>>>(ei, ebuf0, sums0, proj0, out0);
  k_elu<<<NNODES, 256, 0, stream>>>(out0);
  k_gemm1<true><<<2048, 256, 0, stream>>>(out0, W1, a11, a21, a31, nullptr,
                                          proj1, s1_1, s2_1, s3_1);
  hipMemsetAsync(sums1, 0, (size_t)NNODES * sizeof(float), stream);
  k_gemm1<false><<<2048, 256, 0, stream>>>(out0, Wskip1, nullptr, nullptr,
                                           nullptr, b1, out, nullptr, nullptr,
                                           nullptr);
  k_edge_a1<<<(NEDGES + 255) / 256, 256, 0, stream>>>(ei, s1_1, s2_1, s3_1,
                                                      ebuf1, sums1);
  k_edge_b1<<<NEDGES / 4, 256, 0, stream>>>(ei, ebuf1, sums1, proj1, out);
}

// Round 2
// 1559.743 us; speedup vs baseline: 1.3760x; 1.3760x over previous
//
#include <hip/hip_runtime.h>
#include <hip/hip_bf16.h>
#include <math.h>

#define NNODES 100000
#define NEDGES 500000
#define NB_SCAN 391  // ceil(NNODES/256)

// ================= CSR build: degree histogram over both endpoint lists ======
// Endpoint arrays ei[E..2E) (tgt) and ei[2E..3E) (dis) are contiguous.
__global__ void k_deg(const int* __restrict__ ei, int* __restrict__ deg) {
  const int idx = blockIdx.x * 256 + threadIdx.x;
  if (idx < 2 * NEDGES) atomicAdd(&deg[ei[NEDGES + idx]], 1);
}

__global__ void k_scan1(const int* __restrict__ deg, int* __restrict__ offs,
                        int* __restrict__ bsums) {
  __shared__ int sh[256];
  const int t = threadIdx.x;
  const int i = blockIdx.x * 256 + t;
  const int v = (i < NNODES) ? deg[i] : 0;
  sh[t] = v;
  __syncthreads();
  for (int d = 1; d < 256; d <<= 1) {
    const int add = (t >= d) ? sh[t - d] : 0;
    __syncthreads();
    sh[t] += add;
    __syncthreads();
  }
  if (i < NNODES) offs[i] = sh[t] - v;  // exclusive
  if (t == 255) bsums[blockIdx.x] = sh[255];
}

__global__ void k_scan2(int* __restrict__ bsums) {
  __shared__ int sh[512];
  const int t = threadIdx.x;
  const int v = (t < NB_SCAN) ? bsums[t] : 0;
  sh[t] = v;
  __syncthreads();
  for (int d = 1; d < 512; d <<= 1) {
    const int add = (t >= d) ? sh[t - d] : 0;
    __syncthreads();
    sh[t] += add;
    __syncthreads();
  }
  if (t < NB_SCAN) bsums[t] = sh[t] - v;  // exclusive
}

__global__ void k_scan3(int* __restrict__ offs, const int* __restrict__ bsums,
                        int* __restrict__ cursor) {
  const int i = blockIdx.x * 256 + threadIdx.x;
  if (i < NNODES) {
    const int o = offs[i] + bsums[blockIdx.x];
    offs[i] = o;
    cursor[i] = o;
  }
  if (i == 0) offs[NNODES] = 2 * NEDGES;
}

__global__ void k_fill(const int* __restrict__ ei, int* __restrict__ cursor,
                       int* __restrict__ adjlist) {
  const int idx = blockIdx.x * 256 + threadIdx.x;
  if (idx >= 2 * NEDGES) return;
  const int n = ei[NEDGES + idx];
  const int e = (idx < NEDGES) ? idx : idx - NEDGES;
  const int pos = atomicAdd(&cursor[n], 1);
  adjlist[pos] = e;
}

// ================= Layer 0 projection + scores ================================
__global__ __launch_bounds__(256) void k_proj0(
    const float* __restrict__ x, const float* __restrict__ W0,
    const float* __restrict__ a1, const float* __restrict__ a2,
    const float* __restrict__ a3,
    float* __restrict__ proj0, float* __restrict__ s1,
    float* __restrict__ s2, float* __restrict__ s3) {
  __shared__ float xs[32 * 64];
  const int t = threadIdx.x;
  const int base = blockIdx.x * 32;
  float w[64];
#pragma unroll
  for (int q = 0; q < 16; ++q) {
    float4 v = ((const float4*)W0)[t * 16 + q];
    w[q * 4 + 0] = v.x; w[q * 4 + 1] = v.y; w[q * 4 + 2] = v.z; w[q * 4 + 3] = v.w;
  }
  const float a1v = a1[t], a2v = a2[t], a3v = a3[t];
  for (int idx = t; idx < 32 * 64; idx += 256) xs[idx] = x[base * 64 + idx];
  __syncthreads();
  const int lane = t & 63, head = t >> 6;
  for (int i = 0; i < 32; ++i) {
    float acc = 0.f;
#pragma unroll
    for (int k = 0; k < 64; ++k) acc = fmaf(xs[i * 64 + k], w[k], acc);
    const int node = base + i;
    proj0[(size_t)node * 256 + t] = acc;
    float v1 = acc * a1v, v2 = acc * a2v, v3 = acc * a3v;
#pragma unroll
    for (int off = 32; off > 0; off >>= 1) {
      v1 += __shfl_xor(v1, off, 64);
      v2 += __shfl_xor(v2, off, 64);
      v3 += __shfl_xor(v3, off, 64);
    }
    if (lane == 0) {
      s1[node * 4 + head] = v1;
      s2[node * 4 + head] = v2;
      s3[node * 4 + head] = v3;
    }
  }
}

// ================= Layer 0 softmax denominators (gather, no atomics) ==========
__global__ void k_sums0(const int* __restrict__ ei, const int* __restrict__ offs,
                        const int* __restrict__ adjlist,
                        const float* __restrict__ s1, const float* __restrict__ s2,
                        const float* __restrict__ s3, float* __restrict__ sums) {
  const int idx = blockIdx.x * 256 + threadIdx.x;  // < N*4
  if (idx >= NNODES * 4) return;
  const int n = idx >> 2, h = idx & 3;
  const int beg = offs[n], end = offs[n + 1];
  float acc = 0.f;
  for (int j = beg; j < end; ++j) {
    const int e = adjlist[j];
    const int drug = ei[e], tgt = ei[NEDGES + e], dis = ei[2 * NEDGES + e];
    float s = s1[drug * 4 + h] + s2[tgt * 4 + h] + s3[dis * 4 + h];
    s = s > 0.f ? s : 0.2f * s;
    acc += __expf(s);
  }
  sums[idx] = acc;
}

// ================= Layer 0 fused aggregate + skip + bias + elu ================
// One block per node; wave w = head w; lane = feature.
__global__ __launch_bounds__(256) void k_agg0(
    const int* __restrict__ ei, const int* __restrict__ offs,
    const int* __restrict__ adjlist, const float* __restrict__ s1,
    const float* __restrict__ s2, const float* __restrict__ s3,
    const float* __restrict__ sums, const float* __restrict__ proj0,
    const float* __restrict__ x, const float* __restrict__ b0,
    float* __restrict__ out0) {
  const int n = blockIdx.x;
  const int t = threadIdx.x;
  const int h = t >> 6, lane = t & 63;
  const int beg = offs[n], end = offs[n + 1];
  float acc = 0.f, acc2 = 0.f;
  int j = beg;
  for (; j + 1 < end; j += 2) {
    const int e0 = adjlist[j], e1 = adjlist[j + 1];
    const int d0 = ei[e0], t0 = ei[NEDGES + e0], x0 = ei[2 * NEDGES + e0];
    const int d1 = ei[e1], t1 = ei[NEDGES + e1], x1 = ei[2 * NEDGES + e1];
    float sa = s1[d0 * 4 + h] + s2[t0 * 4 + h] + s3[x0 * 4 + h];
    float sb = s1[d1 * 4 + h] + s2[t1 * 4 + h] + s3[x1 * 4 + h];
    const float p0 = proj0[(size_t)d0 * 256 + t];
    const float p1 = proj0[(size_t)d1 * 256 + t];
    sa = sa > 0.f ? sa : 0.2f * sa;
    sb = sb > 0.f ? sb : 0.2f * sb;
    const float att0 = __expf(sa) / (sums[t0 * 4 + h] + sums[x0 * 4 + h] + 1e-16f);
    const float att1 = __expf(sb) / (sums[t1 * 4 + h] + sums[x1 * 4 + h] + 1e-16f);
    acc = fmaf(p0, att0, acc);
    acc2 = fmaf(p1, att1, acc2);
  }
  if (j < end) {
    const int e0 = adjlist[j];
    const int d0 = ei[e0], t0 = ei[NEDGES + e0], x0 = ei[2 * NEDGES + e0];
    float sa = s1[d0 * 4 + h] + s2[t0 * 4 + h] + s3[x0 * 4 + h];
    sa = sa > 0.f ? sa : 0.2f * sa;
    const float att0 = __expf(sa) / (sums[t0 * 4 + h] + sums[x0 * 4 + h] + 1e-16f);
    acc = fmaf(proj0[(size_t)d0 * 256 + t], att0, acc);
  }
  acc += acc2;
  const float v = acc + x[n * 64 + lane] + b0[t];
  out0[(size_t)n * 256 + t] = v > 0.f ? v : expm1f(v);
}

// ================= Layer 1 GEMM (unchanged) ===================================
template <bool DO_S>
__global__ __launch_bounds__(256) void k_gemm1(
    const float* __restrict__ h, const float* __restrict__ W,
    const float* __restrict__ a1, const float* __restrict__ a2,
    const float* __restrict__ a3, const float* __restrict__ b1,
    float* __restrict__ outv, float* __restrict__ s1, float* __restrict__ s2,
    float* __restrict__ s3) {
  __shared__ float wlds[256 * 64];  // [k][of]
  const int t = threadIdx.x;
  for (int idx = t; idx < 256 * 64; idx += 256) {
    const int k = idx >> 6, of = idx & 63;
    wlds[idx] = W[of * 256 + k];
  }
  __syncthreads();
  const int lane = t & 63, wid = t >> 6;
  const int gw = blockIdx.x * 4 + wid, nw = gridDim.x * 4;
  float a1v = 0.f, a2v = 0.f, a3v = 0.f, b1v = 0.f;
  if (DO_S) { a1v = a1[lane]; a2v = a2[lane]; a3v = a3[lane]; }
  else { b1v = b1[lane]; }
  for (int node = gw; node < NNODES; node += nw) {
    const float4* hrow = (const float4*)(h + (size_t)node * 256);
    float acc = 0.f;
#pragma unroll 4
    for (int kq = 0; kq < 64; ++kq) {
      const float4 hv = hrow[kq];
      const int kb = kq * 4;
      acc = fmaf(hv.x, wlds[(kb + 0) * 64 + lane], acc);
      acc = fmaf(hv.y, wlds[(kb + 1) * 64 + lane], acc);
      acc = fmaf(hv.z, wlds[(kb + 2) * 64 + lane], acc);
      acc = fmaf(hv.w, wlds[(kb + 3) * 64 + lane], acc);
    }
    if (DO_S) {
      outv[(size_t)node * 64 + lane] = acc;
      float v1 = acc * a1v, v2 = acc * a2v, v3 = acc * a3v;
#pragma unroll
      for (int off = 32; off > 0; off >>= 1) {
        v1 += __shfl_xor(v1, off, 64);
        v2 += __shfl_xor(v2, off, 64);
        v3 += __shfl_xor(v3, off, 64);
      }
      if (lane == 0) { s1[node] = v1; s2[node] = v2; s3[node] = v3; }
    } else {
      outv[(size_t)node * 64 + lane] = acc + b1v;
    }
  }
}

// ================= Layer 1 denominators (gather) ==============================
__global__ void k_sums1(const int* __restrict__ ei, const int* __restrict__ offs,
                        const int* __restrict__ adjlist,
                        const float* __restrict__ s1, const float* __restrict__ s2,
                        const float* __restrict__ s3, float* __restrict__ sums) {
  const int n = blockIdx.x * 256 + threadIdx.x;
  if (n >= NNODES) return;
  const int beg = offs[n], end = offs[n + 1];
  float acc = 0.f;
  for (int j = beg; j < end; ++j) {
    const int e = adjlist[j];
    float s = s1[ei[e]] + s2[ei[NEDGES + e]] + s3[ei[2 * NEDGES + e]];
    s = s > 0.f ? s : 0.2f * s;
    acc += __expf(s);
  }
  sums[n] = acc;
}

// ================= Layer 1 aggregate: out[n] += sum(msg) ======================
// One wave per node; 4 nodes per block.
__global__ __launch_bounds__(256) void k_agg1(
    const int* __restrict__ ei, const int* __restrict__ offs,
    const int* __restrict__ adjlist, const float* __restrict__ s1,
    const float* __restrict__ s2, const float* __restrict__ s3,
    const float* __restrict__ sums, const float* __restrict__ proj1,
    float* __restrict__ dout) {
  const int lane = threadIdx.x & 63, wid = threadIdx.x >> 6;
  const int n = blockIdx.x * 4 + wid;
  if (n >= NNODES) return;
  const int beg = offs[n], end = offs[n + 1];
  float acc = 0.f, acc2 = 0.f;
  int j = beg;
  for (; j + 1 < end; j += 2) {
    const int e0 = adjlist[j], e1 = adjlist[j + 1];
    const int d0 = ei[e0], t0 = ei[NEDGES + e0], x0 = ei[2 * NEDGES + e0];
    const int d1 = ei[e1], t1 = ei[NEDGES + e1], x1 = ei[2 * NEDGES + e1];
    float sa = s1[d0] + s2[t0] + s3[x0];
    float sb = s1[d1] + s2[t1] + s3[x1];
    const float p0 = proj1[(size_t)d0 * 64 + lane];
    const float p1 = proj1[(size_t)d1 * 64 + lane];
    sa = sa > 0.f ? sa : 0.2f * sa;
    sb = sb > 0.f ? sb : 0.2f * sb;
    acc = fmaf(p0, __expf(sa) / (sums[t0] + sums[x0] + 1e-16f), acc);
    acc2 = fmaf(p1, __expf(sb) / (sums[t1] + sums[x1] + 1e-16f), acc2);
  }
  if (j < end) {
    const int e0 = adjlist[j];
    const int d0 = ei[e0], t0 = ei[NEDGES + e0], x0 = ei[2 * NEDGES + e0];
    float sa = s1[d0] + s2[t0] + s3[x0];
    sa = sa > 0.f ? sa : 0.2f * sa;
    acc = fmaf(proj1[(size_t)d0 * 64 + lane],
               __expf(sa) / (sums[t0] + sums[x0] + 1e-16f), acc);
  }
  acc += acc2;
  dout[(size_t)n * 64 + lane] += acc;  // only this wave touches node n
}

extern "C" void kernel_launch(void* const* d_in, const int* in_sizes, int n_in,
                              void* d_out, int out_size, void* d_ws, size_t ws_size,
                              hipStream_t stream) {
  const float* x = (const float*)d_in[0];
  const int* ei = (const int*)d_in[1];
  const float* W0 = (const float*)d_in[2];
  const float* a10 = (const float*)d_in[3];
  const float* a20 = (const float*)d_in[4];
  const float* a30 = (const float*)d_in[5];
  // d_in[6] = Wskip0: unused (layer-0 skip is identity, F==DIN)
  const float* b0 = (const float*)d_in[7];
  const float* W1 = (const float*)d_in[8];
  const float* a11 = (const float*)d_in[9];
  const float* a21 = (const float*)d_in[10];
  const float* a31 = (const float*)d_in[11];
  const float* Wskip1 = (const float*)d_in[12];
  const float* b1 = (const float*)d_in[13];
  float* out = (float*)d_out;

  // ---- Workspace layout: 53.9M floats = 215.6 MB (< 219.2 MB used in R1) ----
  float* A = (float*)d_ws;                      // 25.6M: proj0 | later layer-1
  float* B = A + (size_t)NNODES * 256;          // 25.6M: out0 | ints during build
  float* D = B + (size_t)NNODES * 256;          // 1.2M: s1_0,s2_0,s3_0
  float* S = D + (size_t)NNODES * 12;           // 0.4M: sums0
  int* adjlist = (int*)(S + (size_t)NNODES * 4);  // 1.0M ints
  int* offs = adjlist + 2 * NEDGES;             // 100001 ints

  float* proj0 = A;
  float* out0 = B;
  float* s1_0 = D;
  float* s2_0 = s1_0 + (size_t)NNODES * 4;
  float* s3_0 = s2_0 + (size_t)NNODES * 4;
  float* sums0 = S;
  // build-time int scratch in B (dead before out0 is written):
  int* deg = (int*)B;
  int* cursor = deg + NNODES;
  int* bsums = cursor + NNODES;                 // NB_SCAN ints
  // layer-1 aliases in A (proj0 dead after k_agg0):
  float* proj1 = A;                             // N*64
  float* s1_1 = A + (size_t)NNODES * 64;
  float* s2_1 = s1_1 + NNODES;
  float* s3_1 = s2_1 + NNODES;
  float* sums1 = s3_1 + NNODES;

  // ---- CSR build (shared by both layers) ----
  hipMemsetAsync(deg, 0, NNODES * sizeof(int), stream);
  k_deg<<<(2 * NEDGES + 255) / 256, 256, 0, stream>>>(ei, deg);
  k_scan1<<<NB_SCAN, 256, 0, stream>>>(deg, offs, bsums);
  k_scan2<<<1, 512, 0, stream>>>(bsums);
  k_scan3<<<NB_SCAN, 256, 0, stream>>>(offs, bsums, cursor);
  k_fill<<<(2 * NEDGES + 255) / 256, 256, 0, stream>>>(ei, cursor, adjlist);

  // ---- Layer 0 ----
  k_proj0<<<NNODES / 32, 256, 0, stream>>>(x, W0, a10, a20, a30, proj0, s1_0,
                                           s2_0, s3_0);
  k_sums0<<<(NNODES * 4 + 255) / 256, 256, 0, stream>>>(ei, offs, adjlist, s1_0,
                                                        s2_0, s3_0, sums0);
  k_agg0<<<NNODES, 256, 0, stream>>>(ei, offs, adjlist, s1_0, s2_0, s3_0, sums0,
                                     proj0, x, b0, out0);

  // ---- Layer 1 ----
  k_gemm1<true><<<2048, 256, 0, stream>>>(out0, W1, a11, a21, a31, nullptr,
                                          proj1, s1_1, s2_1, s3_1);
  k_gemm1<false><<<2048, 256, 0, stream>>>(out0, Wskip1, nullptr, nullptr,
                                           nullptr, b1, out, nullptr, nullptr,
                                           nullptr);
  k_sums1<<<(NNODES + 255) / 256, 256, 0, stream>>>(ei, offs, adjlist, s1_1,
                                                    s2_1, s3_1, sums1);
  k_agg1<<<(NNODES + 3) / 4, 256, 0, stream>>>(ei, offs, adjlist, s1_1, s2_1,
                                               s3_1, sums1, proj1, out);
}

// Round 3
// 1193.458 us; speedup vs baseline: 1.7983x; 1.3069x over previous
//
#include <hip/hip_runtime.h>
#include <hip/hip_bf16.h>
#include <math.h>

#define NNODES 100000
#define NEDGES 500000
#define NB_SCAN 391  // ceil(NNODES/256)

// ================= CSR build ==================================================
__global__ void k_deg(const int* __restrict__ ei, int* __restrict__ deg) {
  const int idx = blockIdx.x * 256 + threadIdx.x;
  if (idx < 2 * NEDGES) atomicAdd(&deg[ei[NEDGES + idx]], 1);
}

__global__ void k_scan1(const int* __restrict__ deg, int* __restrict__ offs,
                        int* __restrict__ bsums) {
  __shared__ int sh[256];
  const int t = threadIdx.x;
  const int i = blockIdx.x * 256 + t;
  const int v = (i < NNODES) ? deg[i] : 0;
  sh[t] = v;
  __syncthreads();
  for (int d = 1; d < 256; d <<= 1) {
    const int add = (t >= d) ? sh[t - d] : 0;
    __syncthreads();
    sh[t] += add;
    __syncthreads();
  }
  if (i < NNODES) offs[i] = sh[t] - v;  // exclusive
  if (t == 255) bsums[blockIdx.x] = sh[255];
}

__global__ void k_scan2(int* __restrict__ bsums) {
  __shared__ int sh[512];
  const int t = threadIdx.x;
  const int v = (t < NB_SCAN) ? bsums[t] : 0;
  sh[t] = v;
  __syncthreads();
  for (int d = 1; d < 512; d <<= 1) {
    const int add = (t >= d) ? sh[t - d] : 0;
    __syncthreads();
    sh[t] += add;
    __syncthreads();
  }
  if (t < NB_SCAN) bsums[t] = sh[t] - v;  // exclusive
}

__global__ void k_scan3(int* __restrict__ offs, const int* __restrict__ bsums,
                        int* __restrict__ cursor) {
  const int i = blockIdx.x * 256 + threadIdx.x;
  if (i < NNODES) {
    const int o = offs[i] + bsums[blockIdx.x];
    offs[i] = o;
    cursor[i] = o;
  }
  if (i == 0) offs[NNODES] = 2 * NEDGES;
}

__global__ void k_fill(const int* __restrict__ ei, int* __restrict__ cursor,
                       int* __restrict__ adjlist) {
  const int idx = blockIdx.x * 256 + threadIdx.x;
  if (idx >= 2 * NEDGES) return;
  const int n = ei[NEDGES + idx];
  const int e = (idx < NEDGES) ? idx : idx - NEDGES;
  const int pos = atomicAdd(&cursor[n], 1);
  adjlist[pos] = e;
}

// ================= Layer 0 projection (no LDS: uniform x loads, W0 in regs) ==
__global__ __launch_bounds__(256) void k_proj0(
    const float* __restrict__ x, const float* __restrict__ W0,
    const float* __restrict__ a1, const float* __restrict__ a2,
    const float* __restrict__ a3,
    __hip_bfloat16* __restrict__ proj0, float* __restrict__ s1,
    float* __restrict__ s2, float* __restrict__ s3) {
  const int t = threadIdx.x;
  const int base = blockIdx.x * 32;
  float w[64];
#pragma unroll
  for (int q = 0; q < 16; ++q) {
    float4 v = ((const float4*)W0)[t * 16 + q];
    w[q * 4 + 0] = v.x; w[q * 4 + 1] = v.y; w[q * 4 + 2] = v.z; w[q * 4 + 3] = v.w;
  }
  const float a1v = a1[t], a2v = a2[t], a3v = a3[t];
  const int lane = t & 63, head = t >> 6;
  for (int i = 0; i < 32; ++i) {
    const int node = base + i;
    const float4* xr = (const float4*)(x + (size_t)node * 64);
    float acc = 0.f;
#pragma unroll
    for (int q = 0; q < 16; ++q) {
      const float4 xv = xr[q];  // wave-uniform broadcast
      acc = fmaf(xv.x, w[q * 4 + 0], acc);
      acc = fmaf(xv.y, w[q * 4 + 1], acc);
      acc = fmaf(xv.z, w[q * 4 + 2], acc);
      acc = fmaf(xv.w, w[q * 4 + 3], acc);
    }
    proj0[(size_t)node * 256 + t] = __float2bfloat16(acc);
    float v1 = acc * a1v, v2 = acc * a2v, v3 = acc * a3v;
#pragma unroll
    for (int off = 32; off > 0; off >>= 1) {
      v1 += __shfl_xor(v1, off, 64);
      v2 += __shfl_xor(v2, off, 64);
      v3 += __shfl_xor(v3, off, 64);
    }
    if (lane == 0) {
      s1[node * 4 + head] = v1;
      s2[node * 4 + head] = v2;
      s3[node * 4 + head] = v3;
    }
  }
}

// ================= Layer 0 attention precompute ===============================
__global__ void k_escore0(const int* __restrict__ ei, const float* __restrict__ s1,
                          const float* __restrict__ s2, const float* __restrict__ s3,
                          float* __restrict__ ebuf) {
  const int e = blockIdx.x * 256 + threadIdx.x;
  if (e >= NEDGES) return;
  const int d = ei[e], tg = ei[NEDGES + e], ds = ei[2 * NEDGES + e];
  const float4 A = ((const float4*)s1)[d];
  const float4 B = ((const float4*)s2)[tg];
  const float4 C = ((const float4*)s3)[ds];
  float4 r;
  float s;
  s = A.x + B.x + C.x; s = s > 0.f ? s : 0.2f * s; r.x = __expf(s);
  s = A.y + B.y + C.y; s = s > 0.f ? s : 0.2f * s; r.y = __expf(s);
  s = A.z + B.z + C.z; s = s > 0.f ? s : 0.2f * s; r.z = __expf(s);
  s = A.w + B.w + C.w; s = s > 0.f ? s : 0.2f * s; r.w = __expf(s);
  ((float4*)ebuf)[e] = r;
}

__global__ void k_sums0(const int* __restrict__ offs, const int* __restrict__ adjlist,
                        const float* __restrict__ ebuf, float* __restrict__ sums) {
  const int n = blockIdx.x * 256 + threadIdx.x;
  if (n >= NNODES) return;
  const int beg = offs[n], end = offs[n + 1];
  float4 acc = make_float4(0.f, 0.f, 0.f, 0.f);
  for (int j = beg; j < end; ++j) {
    const float4 eb = ((const float4*)ebuf)[adjlist[j]];
    acc.x += eb.x; acc.y += eb.y; acc.z += eb.z; acc.w += eb.w;
  }
  ((float4*)sums)[n] = acc;
}

__global__ void k_att0(const int* __restrict__ ei, const float* __restrict__ sums,
                       float* __restrict__ ebuf) {
  const int e = blockIdx.x * 256 + threadIdx.x;
  if (e >= NEDGES) return;
  const int tg = ei[NEDGES + e], ds = ei[2 * NEDGES + e];
  const float4 st = ((const float4*)sums)[tg];
  const float4 sd = ((const float4*)sums)[ds];
  float4 eb = ((const float4*)ebuf)[e];
  eb.x /= (st.x + sd.x + 1e-16f);
  eb.y /= (st.y + sd.y + 1e-16f);
  eb.z /= (st.z + sd.z + 1e-16f);
  eb.w /= (st.w + sd.w + 1e-16f);
  ((float4*)ebuf)[e] = eb;
}

// ================= Layer 0 aggregate + identity skip + bias + elu =============
__global__ __launch_bounds__(256) void k_agg0(
    const int* __restrict__ ei, const int* __restrict__ offs,
    const int* __restrict__ adjlist, const float* __restrict__ ebuf,
    const __hip_bfloat16* __restrict__ proj0, const float* __restrict__ x,
    const float* __restrict__ b0, float* __restrict__ out0) {
  const int n = blockIdx.x;
  const int t = threadIdx.x;
  const int h = t >> 6, lane = t & 63;
  const int beg = offs[n], end = offs[n + 1];
  float acc = 0.f, acc2 = 0.f;
  int j = beg;
  for (; j + 1 < end; j += 2) {
    const int e0 = adjlist[j], e1 = adjlist[j + 1];
    const int d0 = ei[e0], d1 = ei[e1];
    const float at0 = ebuf[e0 * 4 + h];
    const float at1 = ebuf[e1 * 4 + h];
    const float p0 = __bfloat162float(proj0[(size_t)d0 * 256 + t]);
    const float p1 = __bfloat162float(proj0[(size_t)d1 * 256 + t]);
    acc = fmaf(p0, at0, acc);
    acc2 = fmaf(p1, at1, acc2);
  }
  if (j < end) {
    const int e0 = adjlist[j];
    const int d0 = ei[e0];
    const float at0 = ebuf[e0 * 4 + h];
    acc = fmaf(__bfloat162float(proj0[(size_t)d0 * 256 + t]), at0, acc);
  }
  acc += acc2;
  const float v = acc + x[n * 64 + lane] + b0[t];
  out0[(size_t)n * 256 + t] = v > 0.f ? v : expm1f(v);
}

// ================= Layer 1 GEMM: 8 nodes per wave (LDS read amortized 8x) =====
#define NGROUPS 12500  // NNODES / 8
template <bool DO_S>
__global__ __launch_bounds__(256) void k_gemm1(
    const float* __restrict__ h, const float* __restrict__ W,
    const float* __restrict__ a1, const float* __restrict__ a2,
    const float* __restrict__ a3, const float* __restrict__ b1,
    __hip_bfloat16* __restrict__ projb, float* __restrict__ outf,
    float* __restrict__ s1, float* __restrict__ s2, float* __restrict__ s3) {
  __shared__ float wlds[256 * 64];  // [k][of]
  const int t = threadIdx.x;
  for (int idx = t; idx < 256 * 64; idx += 256) {
    const int k = idx >> 6, of = idx & 63;
    wlds[idx] = W[of * 256 + k];
  }
  __syncthreads();
  const int lane = t & 63, wid = t >> 6;
  const int g0 = blockIdx.x * 4 + wid, ng = gridDim.x * 4;
  float a1v = 0.f, a2v = 0.f, a3v = 0.f, b1v = 0.f;
  if (DO_S) { a1v = a1[lane]; a2v = a2[lane]; a3v = a3[lane]; }
  else { b1v = b1[lane]; }
  for (int g = g0; g < NGROUPS; g += ng) {
    const int node = g * 8;
    const float* hb = h + (size_t)node * 256;
    float ac0 = 0.f, ac1 = 0.f, ac2 = 0.f, ac3 = 0.f;
    float ac4 = 0.f, ac5 = 0.f, ac6 = 0.f, ac7 = 0.f;
#pragma unroll 4
    for (int kq = 0; kq < 64; ++kq) {
      const int kb = kq * 4;
      const float w0 = wlds[(kb + 0) * 64 + lane];
      const float w1 = wlds[(kb + 1) * 64 + lane];
      const float w2 = wlds[(kb + 2) * 64 + lane];
      const float w3 = wlds[(kb + 3) * 64 + lane];
      float4 hv;
#define STEP(i, A)                                                     \
      hv = ((const float4*)(hb + (i) * 256))[kq];                      \
      A = fmaf(hv.x, w0, A); A = fmaf(hv.y, w1, A);                    \
      A = fmaf(hv.z, w2, A); A = fmaf(hv.w, w3, A);
      STEP(0, ac0) STEP(1, ac1) STEP(2, ac2) STEP(3, ac3)
      STEP(4, ac4) STEP(5, ac5) STEP(6, ac6) STEP(7, ac7)
#undef STEP
    }
#define EPI_S(i, A)                                                    \
    {                                                                  \
      projb[(size_t)(node + (i)) * 64 + lane] = __float2bfloat16(A);   \
      float v1 = A * a1v, v2 = A * a2v, v3 = A * a3v;                  \
      _Pragma("unroll")                                                \
      for (int off = 32; off > 0; off >>= 1) {                         \
        v1 += __shfl_xor(v1, off, 64);                                 \
        v2 += __shfl_xor(v2, off, 64);                                 \
        v3 += __shfl_xor(v3, off, 64);                                 \
      }                                                                \
      if (lane == 0) {                                                 \
        s1[node + (i)] = v1; s2[node + (i)] = v2; s3[node + (i)] = v3; \
      }                                                                \
    }
#define EPI_O(i, A) outf[(size_t)(node + (i)) * 64 + lane] = A + b1v;
    if (DO_S) {
      EPI_S(0, ac0) EPI_S(1, ac1) EPI_S(2, ac2) EPI_S(3, ac3)
      EPI_S(4, ac4) EPI_S(5, ac5) EPI_S(6, ac6) EPI_S(7, ac7)
    } else {
      EPI_O(0, ac0) EPI_O(1, ac1) EPI_O(2, ac2) EPI_O(3, ac3)
      EPI_O(4, ac4) EPI_O(5, ac5) EPI_O(6, ac6) EPI_O(7, ac7)
    }
#undef EPI_S
#undef EPI_O
  }
}

// ================= Layer 1 attention precompute ===============================
__global__ void k_escore1(const int* __restrict__ ei, const float* __restrict__ s1,
                          const float* __restrict__ s2, const float* __restrict__ s3,
                          float* __restrict__ ebuf) {
  const int e = blockIdx.x * 256 + threadIdx.x;
  if (e >= NEDGES) return;
  float s = s1[ei[e]] + s2[ei[NEDGES + e]] + s3[ei[2 * NEDGES + e]];
  s = s > 0.f ? s : 0.2f * s;
  ebuf[e] = __expf(s);
}

__global__ void k_sums1(const int* __restrict__ offs, const int* __restrict__ adjlist,
                        const float* __restrict__ ebuf, float* __restrict__ sums) {
  const int n = blockIdx.x * 256 + threadIdx.x;
  if (n >= NNODES) return;
  const int beg = offs[n], end = offs[n + 1];
  float acc = 0.f;
  for (int j = beg; j < end; ++j) acc += ebuf[adjlist[j]];
  sums[n] = acc;
}

__global__ void k_att1(const int* __restrict__ ei, const float* __restrict__ sums,
                       float* __restrict__ ebuf) {
  const int e = blockIdx.x * 256 + threadIdx.x;
  if (e >= NEDGES) return;
  const int tg = ei[NEDGES + e], ds = ei[2 * NEDGES + e];
  ebuf[e] /= (sums[tg] + sums[ds] + 1e-16f);
}

// ================= Layer 1 aggregate (wave per node) ==========================
__global__ __launch_bounds__(256) void k_agg1(
    const int* __restrict__ ei, const int* __restrict__ offs,
    const int* __restrict__ adjlist, const float* __restrict__ ebuf,
    const __hip_bfloat16* __restrict__ proj1, float* __restrict__ dout) {
  const int lane = threadIdx.x & 63, wid = threadIdx.x >> 6;
  const int n = blockIdx.x * 4 + wid;
  if (n >= NNODES) return;
  const int beg = offs[n], end = offs[n + 1];
  float acc = 0.f, acc2 = 0.f;
  int j = beg;
  for (; j + 1 < end; j += 2) {
    const int e0 = adjlist[j], e1 = adjlist[j + 1];
    const int d0 = ei[e0], d1 = ei[e1];
    const float at0 = ebuf[e0], at1 = ebuf[e1];
    const float p0 = __bfloat162float(proj1[(size_t)d0 * 64 + lane]);
    const float p1 = __bfloat162float(proj1[(size_t)d1 * 64 + lane]);
    acc = fmaf(p0, at0, acc);
    acc2 = fmaf(p1, at1, acc2);
  }
  if (j < end) {
    const int e0 = adjlist[j];
    acc = fmaf(__bfloat162float(proj1[(size_t)ei[e0] * 64 + lane]), ebuf[e0], acc);
  }
  dout[(size_t)n * 64 + lane] += acc + acc2;  // single wave owns node n
}

extern "C" void kernel_launch(void* const* d_in, const int* in_sizes, int n_in,
                              void* d_out, int out_size, void* d_ws, size_t ws_size,
                              hipStream_t stream) {
  const float* x = (const float*)d_in[0];
  const int* ei = (const int*)d_in[1];
  const float* W0 = (const float*)d_in[2];
  const float* a10 = (const float*)d_in[3];
  const float* a20 = (const float*)d_in[4];
  const float* a30 = (const float*)d_in[5];
  // d_in[6] = Wskip0: unused (layer-0 skip is identity, F==DIN)
  const float* b0 = (const float*)d_in[7];
  const float* W1 = (const float*)d_in[8];
  const float* a11 = (const float*)d_in[9];
  const float* a21 = (const float*)d_in[10];
  const float* a31 = (const float*)d_in[11];
  const float* Wskip1 = (const float*)d_in[12];
  const float* b1 = (const float*)d_in[13];
  float* out = (float*)d_out;

  // ---- Workspace layout: ~179 MB ----
  __hip_bfloat16* P = (__hip_bfloat16*)d_ws;        // N*256 bf16: proj0 / proj1
  float* out0 = (float*)(P + (size_t)NNODES * 256); // N*256 f32
  float* s1_0 = out0 + (size_t)NNODES * 256;        // N*4 x3
  float* s2_0 = s1_0 + (size_t)NNODES * 4;
  float* s3_0 = s2_0 + (size_t)NNODES * 4;
  float* sums0 = s3_0 + (size_t)NNODES * 4;         // N*4
  float* ebuf0 = sums0 + (size_t)NNODES * 4;        // E*4
  float* s1_1 = ebuf0 + (size_t)NEDGES * 4;         // N x3
  float* s2_1 = s1_1 + NNODES;
  float* s3_1 = s2_1 + NNODES;
  float* sums1 = s3_1 + NNODES;                     // N
  float* ebuf1 = sums1 + NNODES;                    // E
  int* adjlist = (int*)(ebuf1 + NEDGES);            // 2E
  int* offs = adjlist + 2 * NEDGES;                 // N+1
  // CSR-build int scratch aliases out0 (dead until k_agg0):
  int* deg = (int*)out0;
  int* cursor = deg + NNODES;
  int* bsums = cursor + NNODES;

  __hip_bfloat16* proj0 = P;
  __hip_bfloat16* proj1 = P;  // aliases proj0 (dead after k_agg0)

  // ---- CSR build (shared by both layers) ----
  hipMemsetAsync(deg, 0, NNODES * sizeof(int), stream);
  k_deg<<<(2 * NEDGES + 255) / 256, 256, 0, stream>>>(ei, deg);
  k_scan1<<<NB_SCAN, 256, 0, stream>>>(deg, offs, bsums);
  k_scan2<<<1, 512, 0, stream>>>(bsums);
  k_scan3<<<NB_SCAN, 256, 0, stream>>>(offs, bsums, cursor);
  k_fill<<<(2 * NEDGES + 255) / 256, 256, 0, stream>>>(ei, cursor, adjlist);

  // ---- Layer 0 ----
  k_proj0<<<NNODES / 32, 256, 0, stream>>>(x, W0, a10, a20, a30, proj0, s1_0,
                                           s2_0, s3_0);
  k_escore0<<<(NEDGES + 255) / 256, 256, 0, stream>>>(ei, s1_0, s2_0, s3_0, ebuf0);
  k_sums0<<<(NNODES + 255) / 256, 256, 0, stream>>>(offs, adjlist, ebuf0, sums0);
  k_att0<<<(NEDGES + 255) / 256, 256, 0, stream>>>(ei, sums0, ebuf0);
  k_agg0<<<NNODES, 256, 0, stream>>>(ei, offs, adjlist, ebuf0, proj0, x, b0, out0);

  // ---- Layer 1 ----
  k_gemm1<true><<<512, 256, 0, stream>>>(out0, W1, a11, a21, a31, nullptr,
                                         proj1, nullptr, s1_1, s2_1, s3_1);
  k_gemm1<false><<<512, 256, 0, stream>>>(out0, Wskip1, nullptr, nullptr,
                                          nullptr, b1, nullptr, out, nullptr,
                                          nullptr, nullptr);
  k_escore1<<<(NEDGES + 255) / 256, 256, 0, stream>>>(ei, s1_1, s2_1, s3_1, ebuf1);
  k_sums1<<<(NNODES + 255) / 256, 256, 0, stream>>>(offs, adjlist, ebuf1, sums1);
  k_att1<<<(NEDGES + 255) / 256, 256, 0, stream>>>(ei, sums1, ebuf1);
  k_agg1<<<(NNODES + 3) / 4, 256, 0, stream>>>(ei, offs, adjlist, ebuf1, proj1, out);
}

// Round 4
// 1049.872 us; speedup vs baseline: 2.0442x; 1.1368x over previous
//
#include <hip/hip_runtime.h>
#include <hip/hip_bf16.h>
#include <math.h>

#define NNODES 100000
#define NEDGES 500000
#define NB_SCAN 391  // ceil(NNODES/256)

// ================= CSR build ==================================================
__global__ void k_deg(const int* __restrict__ ei, int* __restrict__ deg) {
  const int idx = blockIdx.x * 256 + threadIdx.x;
  if (idx < 2 * NEDGES) atomicAdd(&deg[ei[NEDGES + idx]], 1);
}

__global__ void k_scan1(const int* __restrict__ deg, int* __restrict__ offs,
                        int* __restrict__ bsums) {
  __shared__ int sh[256];
  const int t = threadIdx.x;
  const int i = blockIdx.x * 256 + t;
  const int v = (i < NNODES) ? deg[i] : 0;
  sh[t] = v;
  __syncthreads();
  for (int d = 1; d < 256; d <<= 1) {
    const int add = (t >= d) ? sh[t - d] : 0;
    __syncthreads();
    sh[t] += add;
    __syncthreads();
  }
  if (i < NNODES) offs[i] = sh[t] - v;  // exclusive
  if (t == 255) bsums[blockIdx.x] = sh[255];
}

__global__ void k_scan2(int* __restrict__ bsums) {
  __shared__ int sh[512];
  const int t = threadIdx.x;
  const int v = (t < NB_SCAN) ? bsums[t] : 0;
  sh[t] = v;
  __syncthreads();
  for (int d = 1; d < 512; d <<= 1) {
    const int add = (t >= d) ? sh[t - d] : 0;
    __syncthreads();
    sh[t] += add;
    __syncthreads();
  }
  if (t < NB_SCAN) bsums[t] = sh[t] - v;  // exclusive
}

__global__ void k_scan3(int* __restrict__ offs, const int* __restrict__ bsums,
                        int* __restrict__ cursor) {
  const int i = blockIdx.x * 256 + threadIdx.x;
  if (i < NNODES) {
    const int o = offs[i] + bsums[blockIdx.x];
    offs[i] = o;
    cursor[i] = o;
  }
  if (i == 0) offs[NNODES] = 2 * NEDGES;
}

// Fill slot records: drug, other-receiver, edge id, and layer-0 exp-scores.
__global__ void k_fill2(const int* __restrict__ ei, int* __restrict__ cursor,
                        const float* __restrict__ s1, const float* __restrict__ s2,
                        const float* __restrict__ s3, int* __restrict__ drugA,
                        int* __restrict__ otherA, int* __restrict__ eidxA,
                        float* __restrict__ esx) {
  const int idx = blockIdx.x * 256 + threadIdx.x;
  if (idx >= 2 * NEDGES) return;
  const int n = ei[NEDGES + idx];  // this slot's receiver
  const int e = (idx < NEDGES) ? idx : idx - NEDGES;
  const int drug = ei[e], tgt = ei[NEDGES + e], dis = ei[2 * NEDGES + e];
  const int other = (idx < NEDGES) ? dis : tgt;
  const float4 A = ((const float4*)s1)[drug];
  const float4 B = ((const float4*)s2)[tgt];
  const float4 C = ((const float4*)s3)[dis];
  float4 r;
  float s;
  s = A.x + B.x + C.x; s = s > 0.f ? s : 0.2f * s; r.x = __expf(s);
  s = A.y + B.y + C.y; s = s > 0.f ? s : 0.2f * s; r.y = __expf(s);
  s = A.z + B.z + C.z; s = s > 0.f ? s : 0.2f * s; r.z = __expf(s);
  s = A.w + B.w + C.w; s = s > 0.f ? s : 0.2f * s; r.w = __expf(s);
  const int pos = atomicAdd(&cursor[n], 1);
  drugA[pos] = drug;
  otherA[pos] = other;
  eidxA[pos] = e;
  ((float4*)esx)[pos] = r;
}

// ================= Layer 0 projection (W0 in regs, uniform x loads) ===========
__global__ __launch_bounds__(256) void k_proj0(
    const float* __restrict__ x, const float* __restrict__ W0,
    const float* __restrict__ a1, const float* __restrict__ a2,
    const float* __restrict__ a3,
    __hip_bfloat16* __restrict__ proj0, float* __restrict__ s1,
    float* __restrict__ s2, float* __restrict__ s3) {
  const int t = threadIdx.x;
  const int base = blockIdx.x * 32;
  float w[64];
#pragma unroll
  for (int q = 0; q < 16; ++q) {
    float4 v = ((const float4*)W0)[t * 16 + q];
    w[q * 4 + 0] = v.x; w[q * 4 + 1] = v.y; w[q * 4 + 2] = v.z; w[q * 4 + 3] = v.w;
  }
  const float a1v = a1[t], a2v = a2[t], a3v = a3[t];
  const int lane = t & 63, head = t >> 6;
  for (int i = 0; i < 32; ++i) {
    const int node = base + i;
    const float4* xr = (const float4*)(x + (size_t)node * 64);
    float acc = 0.f;
#pragma unroll
    for (int q = 0; q < 16; ++q) {
      const float4 xv = xr[q];  // wave-uniform broadcast
      acc = fmaf(xv.x, w[q * 4 + 0], acc);
      acc = fmaf(xv.y, w[q * 4 + 1], acc);
      acc = fmaf(xv.z, w[q * 4 + 2], acc);
      acc = fmaf(xv.w, w[q * 4 + 3], acc);
    }
    proj0[(size_t)node * 256 + t] = __float2bfloat16(acc);
    float v1 = acc * a1v, v2 = acc * a2v, v3 = acc * a3v;
#pragma unroll
    for (int off = 32; off > 0; off >>= 1) {
      v1 += __shfl_xor(v1, off, 64);
      v2 += __shfl_xor(v2, off, 64);
      v3 += __shfl_xor(v3, off, 64);
    }
    if (lane == 0) {
      s1[node * 4 + head] = v1;
      s2[node * 4 + head] = v2;
      s3[node * 4 + head] = v3;
    }
  }
}

// ================= Layer 0 denominators: sequential segmented sum =============
__global__ void k_sums0(const int* __restrict__ offs, const float* __restrict__ esx,
                        float* __restrict__ sums) {
  const int n = blockIdx.x * 256 + threadIdx.x;
  if (n >= NNODES) return;
  const int beg = offs[n], end = offs[n + 1];
  float4 acc = make_float4(0.f, 0.f, 0.f, 0.f);
  for (int j = beg; j < end; ++j) {
    const float4 v = ((const float4*)esx)[j];
    acc.x += v.x; acc.y += v.y; acc.z += v.z; acc.w += v.w;
  }
  ((float4*)sums)[n] = acc;
}

// ================= Layer 0 aggregate (fused att) + skip + bias + elu ==========
// Block per node; thread t = (head h = t>>6, feature lane = t&63).
__global__ __launch_bounds__(256) void k_agg0(
    const int* __restrict__ offs, const int* __restrict__ drugA,
    const int* __restrict__ otherA, const float* __restrict__ esx,
    const float* __restrict__ sums, const __hip_bfloat16* __restrict__ proj0,
    const float* __restrict__ x, const float* __restrict__ b0,
    float* __restrict__ out0) {
  const int n = blockIdx.x;
  const int t = threadIdx.x;
  const int h = t >> 6, lane = t & 63;
  const int beg = offs[n], end = offs[n + 1];
  const float sn = sums[n * 4 + h];
  float acc0 = 0.f, acc1 = 0.f, acc2 = 0.f, acc3 = 0.f;
  int j = beg;
  for (; j + 3 < end; j += 4) {
#define LD(i)                                                              \
    const int d##i = drugA[j + i];                                         \
    const int o##i = otherA[j + i];                                        \
    const float e##i = esx[(j + i) * 4 + h];                               \
    const float p##i = __bfloat162float(proj0[(size_t)d##i * 256 + t]);    \
    const float so##i = sums[o##i * 4 + h];
    LD(0) LD(1) LD(2) LD(3)
#undef LD
    acc0 = fmaf(p0, e0 / (sn + so0 + 1e-16f), acc0);
    acc1 = fmaf(p1, e1 / (sn + so1 + 1e-16f), acc1);
    acc2 = fmaf(p2, e2 / (sn + so2 + 1e-16f), acc2);
    acc3 = fmaf(p3, e3 / (sn + so3 + 1e-16f), acc3);
  }
  for (; j < end; ++j) {
    const int d0 = drugA[j];
    const int o0 = otherA[j];
    const float e0 = esx[j * 4 + h];
    const float p0 = __bfloat162float(proj0[(size_t)d0 * 256 + t]);
    acc0 = fmaf(p0, e0 / (sn + sums[o0 * 4 + h] + 1e-16f), acc0);
  }
  const float acc = (acc0 + acc1) + (acc2 + acc3);
  const float v = acc + x[n * 64 + lane] + b0[t];
  out0[(size_t)n * 256 + t] = v > 0.f ? v : expm1f(v);
}

// ================= Layer 1 GEMM: 8 nodes per wave =============================
#define NGROUPS 12500  // NNODES / 8
template <bool DO_S>
__global__ __launch_bounds__(256) void k_gemm1(
    const float* __restrict__ h, const float* __restrict__ W,
    const float* __restrict__ a1, const float* __restrict__ a2,
    const float* __restrict__ a3, const float* __restrict__ b1,
    __hip_bfloat16* __restrict__ projb, float* __restrict__ outf,
    float* __restrict__ s1, float* __restrict__ s2, float* __restrict__ s3) {
  __shared__ float wlds[256 * 64];  // [k][of]
  const int t = threadIdx.x;
  for (int idx = t; idx < 256 * 64; idx += 256) {
    const int k = idx >> 6, of = idx & 63;
    wlds[idx] = W[of * 256 + k];
  }
  __syncthreads();
  const int lane = t & 63, wid = t >> 6;
  const int g0 = blockIdx.x * 4 + wid, ng = gridDim.x * 4;
  float a1v = 0.f, a2v = 0.f, a3v = 0.f, b1v = 0.f;
  if (DO_S) { a1v = a1[lane]; a2v = a2[lane]; a3v = a3[lane]; }
  else { b1v = b1[lane]; }
  for (int g = g0; g < NGROUPS; g += ng) {
    const int node = g * 8;
    const float* hb = h + (size_t)node * 256;
    float ac0 = 0.f, ac1 = 0.f, ac2 = 0.f, ac3 = 0.f;
    float ac4 = 0.f, ac5 = 0.f, ac6 = 0.f, ac7 = 0.f;
#pragma unroll 4
    for (int kq = 0; kq < 64; ++kq) {
      const int kb = kq * 4;
      const float w0 = wlds[(kb + 0) * 64 + lane];
      const float w1 = wlds[(kb + 1) * 64 + lane];
      const float w2 = wlds[(kb + 2) * 64 + lane];
      const float w3 = wlds[(kb + 3) * 64 + lane];
      float4 hv;
#define STEP(i, A)                                                     \
      hv = ((const float4*)(hb + (i) * 256))[kq];                      \
      A = fmaf(hv.x, w0, A); A = fmaf(hv.y, w1, A);                    \
      A = fmaf(hv.z, w2, A); A = fmaf(hv.w, w3, A);
      STEP(0, ac0) STEP(1, ac1) STEP(2, ac2) STEP(3, ac3)
      STEP(4, ac4) STEP(5, ac5) STEP(6, ac6) STEP(7, ac7)
#undef STEP
    }
#define EPI_S(i, A)                                                    \
    {                                                                  \
      projb[(size_t)(node + (i)) * 64 + lane] = __float2bfloat16(A);   \
      float v1 = A * a1v, v2 = A * a2v, v3 = A * a3v;                  \
      _Pragma("unroll")                                                \
      for (int off = 32; off > 0; off >>= 1) {                         \
        v1 += __shfl_xor(v1, off, 64);                                 \
        v2 += __shfl_xor(v2, off, 64);                                 \
        v3 += __shfl_xor(v3, off, 64);                                 \
      }                                                                \
      if (lane == 0) {                                                 \
        s1[node + (i)] = v1; s2[node + (i)] = v2; s3[node + (i)] = v3; \
      }                                                                \
    }
#define EPI_O(i, A) outf[(size_t)(node + (i)) * 64 + lane] = A + b1v;
    if (DO_S) {
      EPI_S(0, ac0) EPI_S(1, ac1) EPI_S(2, ac2) EPI_S(3, ac3)
      EPI_S(4, ac4) EPI_S(5, ac5) EPI_S(6, ac6) EPI_S(7, ac7)
    } else {
      EPI_O(0, ac0) EPI_O(1, ac1) EPI_O(2, ac2) EPI_O(3, ac3)
      EPI_O(4, ac4) EPI_O(5, ac5) EPI_O(6, ac6) EPI_O(7, ac7)
    }
#undef EPI_S
#undef EPI_O
  }
}

// ================= Layer 1 attention ==========================================
__global__ void k_escore1(const int* __restrict__ ei, const float* __restrict__ s1,
                          const float* __restrict__ s2, const float* __restrict__ s3,
                          float* __restrict__ ebuf) {
  const int e = blockIdx.x * 256 + threadIdx.x;
  if (e >= NEDGES) return;
  float s = s1[ei[e]] + s2[ei[NEDGES + e]] + s3[ei[2 * NEDGES + e]];
  s = s > 0.f ? s : 0.2f * s;
  ebuf[e] = __expf(s);
}

__global__ void k_sums1(const int* __restrict__ offs, const int* __restrict__ eidxA,
                        const float* __restrict__ ebuf, float* __restrict__ sums) {
  const int n = blockIdx.x * 256 + threadIdx.x;
  if (n >= NNODES) return;
  const int beg = offs[n], end = offs[n + 1];
  float acc = 0.f;
  for (int j = beg; j < end; ++j) acc += ebuf[eidxA[j]];
  sums[n] = acc;
}

// ================= Layer 1 aggregate (fused att), wave per node ===============
__global__ __launch_bounds__(256) void k_agg1(
    const int* __restrict__ offs, const int* __restrict__ drugA,
    const int* __restrict__ otherA, const int* __restrict__ eidxA,
    const float* __restrict__ ebuf, const float* __restrict__ sums,
    const __hip_bfloat16* __restrict__ proj1, float* __restrict__ dout) {
  const int lane = threadIdx.x & 63, wid = threadIdx.x >> 6;
  const int n = blockIdx.x * 4 + wid;
  if (n >= NNODES) return;
  const int beg = offs[n], end = offs[n + 1];
  const float sn = sums[n];
  float acc0 = 0.f, acc1 = 0.f, acc2 = 0.f, acc3 = 0.f;
  int j = beg;
  for (; j + 3 < end; j += 4) {
#define LD(i)                                                              \
    const int d##i = drugA[j + i];                                         \
    const int o##i = otherA[j + i];                                        \
    const float e##i = ebuf[eidxA[j + i]];                                 \
    const float p##i = __bfloat162float(proj1[(size_t)d##i * 64 + lane]);  \
    const float so##i = sums[o##i];
    LD(0) LD(1) LD(2) LD(3)
#undef LD
    acc0 = fmaf(p0, e0 / (sn + so0 + 1e-16f), acc0);
    acc1 = fmaf(p1, e1 / (sn + so1 + 1e-16f), acc1);
    acc2 = fmaf(p2, e2 / (sn + so2 + 1e-16f), acc2);
    acc3 = fmaf(p3, e3 / (sn + so3 + 1e-16f), acc3);
  }
  for (; j < end; ++j) {
    const int d0 = drugA[j];
    const float e0 = ebuf[eidxA[j]];
    const float p0 = __bfloat162float(proj1[(size_t)d0 * 64 + lane]);
    acc0 = fmaf(p0, e0 / (sn + sums[otherA[j]] + 1e-16f), acc0);
  }
  dout[(size_t)n * 64 + lane] += (acc0 + acc1) + (acc2 + acc3);
}

extern "C" void kernel_launch(void* const* d_in, const int* in_sizes, int n_in,
                              void* d_out, int out_size, void* d_ws, size_t ws_size,
                              hipStream_t stream) {
  const float* x = (const float*)d_in[0];
  const int* ei = (const int*)d_in[1];
  const float* W0 = (const float*)d_in[2];
  const float* a10 = (const float*)d_in[3];
  const float* a20 = (const float*)d_in[4];
  const float* a30 = (const float*)d_in[5];
  // d_in[6] = Wskip0: unused (layer-0 skip is identity, F==DIN)
  const float* b0 = (const float*)d_in[7];
  const float* W1 = (const float*)d_in[8];
  const float* a11 = (const float*)d_in[9];
  const float* a21 = (const float*)d_in[10];
  const float* a31 = (const float*)d_in[11];
  const float* Wskip1 = (const float*)d_in[12];
  const float* b1 = (const float*)d_in[13];
  float* out = (float*)d_out;

  // ---- Workspace layout: ~192 MB ----
  __hip_bfloat16* P = (__hip_bfloat16*)d_ws;        // N*256 bf16 (proj0/proj1)
  float* out0 = (float*)(P + (size_t)NNODES * 256); // N*256 f32
  float* s1_0 = out0 + (size_t)NNODES * 256;        // N*4 x3
  float* s2_0 = s1_0 + (size_t)NNODES * 4;
  float* s3_0 = s2_0 + (size_t)NNODES * 4;
  float* sums0 = s3_0 + (size_t)NNODES * 4;         // N*4
  float* esx0 = sums0 + (size_t)NNODES * 4;         // 2E*4 (float4/slot)
  int* drugA = (int*)(esx0 + (size_t)2 * NEDGES * 4);  // 2E
  int* otherA = drugA + 2 * NEDGES;                 // 2E
  int* eidxA = otherA + 2 * NEDGES;                 // 2E
  int* offs = eidxA + 2 * NEDGES;                   // N+1
  float* s1_1 = (float*)(offs + NNODES + 1);        // N x3
  float* s2_1 = s1_1 + NNODES;
  float* s3_1 = s2_1 + NNODES;
  float* sums1 = s3_1 + NNODES;                     // N
  float* ebuf1 = sums1 + NNODES;                    // E
  // CSR-build int scratch aliases out0 (dead until k_agg0 writes out0):
  int* deg = (int*)out0;
  int* cursor = deg + NNODES;
  int* bsums = cursor + NNODES;

  __hip_bfloat16* proj0 = P;
  __hip_bfloat16* proj1 = P;  // aliases proj0 (dead after k_agg0)

  // ---- Layer 0 projection + scores (needed before CSR fill) ----
  k_proj0<<<NNODES / 32, 256, 0, stream>>>(x, W0, a10, a20, a30, proj0, s1_0,
                                           s2_0, s3_0);

  // ---- CSR build with slot records + layer-0 exp-scores ----
  hipMemsetAsync(deg, 0, NNODES * sizeof(int), stream);
  k_deg<<<(2 * NEDGES + 255) / 256, 256, 0, stream>>>(ei, deg);
  k_scan1<<<NB_SCAN, 256, 0, stream>>>(deg, offs, bsums);
  k_scan2<<<1, 512, 0, stream>>>(bsums);
  k_scan3<<<NB_SCAN, 256, 0, stream>>>(offs, bsums, cursor);
  k_fill2<<<(2 * NEDGES + 255) / 256, 256, 0, stream>>>(
      ei, cursor, s1_0, s2_0, s3_0, drugA, otherA, eidxA, esx0);

  // ---- Layer 0 ----
  k_sums0<<<(NNODES + 255) / 256, 256, 0, stream>>>(offs, esx0, sums0);
  k_agg0<<<NNODES, 256, 0, stream>>>(offs, drugA, otherA, esx0, sums0, proj0, x,
                                     b0, out0);

  // ---- Layer 1 ----
  k_gemm1<true><<<512, 256, 0, stream>>>(out0, W1, a11, a21, a31, nullptr,
                                         proj1, nullptr, s1_1, s2_1, s3_1);
  k_gemm1<false><<<512, 256, 0, stream>>>(out0, Wskip1, nullptr, nullptr,
                                          nullptr, b1, nullptr, out, nullptr,
                                          nullptr, nullptr);
  k_escore1<<<(NEDGES + 255) / 256, 256, 0, stream>>>(ei, s1_1, s2_1, s3_1, ebuf1);
  k_sums1<<<(NNODES + 255) / 256, 256, 0, stream>>>(offs, eidxA, ebuf1, sums1);
  k_agg1<<<(NNODES + 3) / 4, 256, 0, stream>>>(offs, drugA, otherA, eidxA, ebuf1,
                                               sums1, proj1, out);
}

// Round 5
// 712.343 us; speedup vs baseline: 3.0128x; 1.4738x over previous
//
#include <hip/hip_runtime.h>
#include <hip/hip_bf16.h>
#include <math.h>

#define NNODES 100000
#define NEDGES 500000
#define NB_SCAN 391  // ceil(NNODES/256)

typedef __attribute__((ext_vector_type(8))) short short8;
typedef __attribute__((ext_vector_type(4))) float f32x4;

// ================= CSR build ==================================================
__global__ void k_deg(const int* __restrict__ ei, int* __restrict__ deg) {
  const int idx = blockIdx.x * 256 + threadIdx.x;
  if (idx < 2 * NEDGES) atomicAdd(&deg[ei[NEDGES + idx]], 1);
}

__global__ void k_scan1(const int* __restrict__ deg, int* __restrict__ offs,
                        int* __restrict__ bsums) {
  __shared__ int sh[256];
  const int t = threadIdx.x;
  const int i = blockIdx.x * 256 + t;
  const int v = (i < NNODES) ? deg[i] : 0;
  sh[t] = v;
  __syncthreads();
  for (int d = 1; d < 256; d <<= 1) {
    const int add = (t >= d) ? sh[t - d] : 0;
    __syncthreads();
    sh[t] += add;
    __syncthreads();
  }
  if (i < NNODES) offs[i] = sh[t] - v;  // exclusive
  if (t == 255) bsums[blockIdx.x] = sh[255];
}

__global__ void k_scan2(int* __restrict__ bsums) {
  __shared__ int sh[512];
  const int t = threadIdx.x;
  const int v = (t < NB_SCAN) ? bsums[t] : 0;
  sh[t] = v;
  __syncthreads();
  for (int d = 1; d < 512; d <<= 1) {
    const int add = (t >= d) ? sh[t - d] : 0;
    __syncthreads();
    sh[t] += add;
    __syncthreads();
  }
  if (t < NB_SCAN) bsums[t] = sh[t] - v;  // exclusive
}

__global__ void k_scan3(int* __restrict__ offs, const int* __restrict__ bsums,
                        int* __restrict__ cursor) {
  const int i = blockIdx.x * 256 + threadIdx.x;
  if (i < NNODES) {
    const int o = offs[i] + bsums[blockIdx.x];
    offs[i] = o;
    cursor[i] = o;
  }
  if (i == 0) offs[NNODES] = 2 * NEDGES;
}

// Fill slot records: drug, other-receiver, edge id, and layer-0 exp-scores.
__global__ void k_fill2(const int* __restrict__ ei, int* __restrict__ cursor,
                        const float* __restrict__ s1, const float* __restrict__ s2,
                        const float* __restrict__ s3, int* __restrict__ drugA,
                        int* __restrict__ otherA, int* __restrict__ eidxA,
                        float* __restrict__ esx) {
  const int idx = blockIdx.x * 256 + threadIdx.x;
  if (idx >= 2 * NEDGES) return;
  const int n = ei[NEDGES + idx];  // this slot's receiver
  const int e = (idx < NEDGES) ? idx : idx - NEDGES;
  const int drug = ei[e], tgt = ei[NEDGES + e], dis = ei[2 * NEDGES + e];
  const int other = (idx < NEDGES) ? dis : tgt;
  const float4 A = ((const float4*)s1)[drug];
  const float4 B = ((const float4*)s2)[tgt];
  const float4 C = ((const float4*)s3)[dis];
  float4 r;
  float s;
  s = A.x + B.x + C.x; s = s > 0.f ? s : 0.2f * s; r.x = __expf(s);
  s = A.y + B.y + C.y; s = s > 0.f ? s : 0.2f * s; r.y = __expf(s);
  s = A.z + B.z + C.z; s = s > 0.f ? s : 0.2f * s; r.z = __expf(s);
  s = A.w + B.w + C.w; s = s > 0.f ? s : 0.2f * s; r.w = __expf(s);
  const int pos = atomicAdd(&cursor[n], 1);
  drugA[pos] = drug;
  otherA[pos] = other;
  eidxA[pos] = e;
  ((float4*)esx)[pos] = r;
}

// ================= Layer 0 projection (W0 in regs, uniform x loads) ===========
__global__ __launch_bounds__(256) void k_proj0(
    const float* __restrict__ x, const float* __restrict__ W0,
    const float* __restrict__ a1, const float* __restrict__ a2,
    const float* __restrict__ a3,
    __hip_bfloat16* __restrict__ proj0, float* __restrict__ s1,
    float* __restrict__ s2, float* __restrict__ s3) {
  const int t = threadIdx.x;
  const int base = blockIdx.x * 32;
  float w[64];
#pragma unroll
  for (int q = 0; q < 16; ++q) {
    float4 v = ((const float4*)W0)[t * 16 + q];
    w[q * 4 + 0] = v.x; w[q * 4 + 1] = v.y; w[q * 4 + 2] = v.z; w[q * 4 + 3] = v.w;
  }
  const float a1v = a1[t], a2v = a2[t], a3v = a3[t];
  const int lane = t & 63, head = t >> 6;
  for (int i = 0; i < 32; ++i) {
    const int node = base + i;
    const float4* xr = (const float4*)(x + (size_t)node * 64);
    float acc = 0.f;
#pragma unroll
    for (int q = 0; q < 16; ++q) {
      const float4 xv = xr[q];  // wave-uniform broadcast
      acc = fmaf(xv.x, w[q * 4 + 0], acc);
      acc = fmaf(xv.y, w[q * 4 + 1], acc);
      acc = fmaf(xv.z, w[q * 4 + 2], acc);
      acc = fmaf(xv.w, w[q * 4 + 3], acc);
    }
    proj0[(size_t)node * 256 + t] = __float2bfloat16(acc);
    float v1 = acc * a1v, v2 = acc * a2v, v3 = acc * a3v;
#pragma unroll
    for (int off = 32; off > 0; off >>= 1) {
      v1 += __shfl_xor(v1, off, 64);
      v2 += __shfl_xor(v2, off, 64);
      v3 += __shfl_xor(v3, off, 64);
    }
    if (lane == 0) {
      s1[node * 4 + head] = v1;
      s2[node * 4 + head] = v2;
      s3[node * 4 + head] = v3;
    }
  }
}

// ================= Layer 0 denominators: sequential segmented sum =============
__global__ void k_sums0(const int* __restrict__ offs, const float* __restrict__ esx,
                        float* __restrict__ sums) {
  const int n = blockIdx.x * 256 + threadIdx.x;
  if (n >= NNODES) return;
  const int beg = offs[n], end = offs[n + 1];
  float4 acc = make_float4(0.f, 0.f, 0.f, 0.f);
  for (int j = beg; j < end; ++j) {
    const float4 v = ((const float4*)esx)[j];
    acc.x += v.x; acc.y += v.y; acc.z += v.z; acc.w += v.w;
  }
  ((float4*)sums)[n] = acc;
}

// ====== Layer 0 aggregate + skip + bias + elu; h -> bf16; layer-1 scores ======
// Block per node; thread t = (head h = t>>6, feature lane = t&63).
// s{1,2,3}_1[n] = sum_k h[n,k]*c{1,2,3}[k]  (c = a^T W1, precomputed).
__global__ __launch_bounds__(256) void k_agg0(
    const int* __restrict__ offs, const int* __restrict__ drugA,
    const int* __restrict__ otherA, const float* __restrict__ esx,
    const float* __restrict__ sums, const __hip_bfloat16* __restrict__ proj0,
    const float* __restrict__ x, const float* __restrict__ b0,
    const float* __restrict__ c1, const float* __restrict__ c2,
    const float* __restrict__ c3, __hip_bfloat16* __restrict__ out0b,
    float* __restrict__ s1_1, float* __restrict__ s2_1,
    float* __restrict__ s3_1) {
  __shared__ float red[12];
  const int n = blockIdx.x;
  const int t = threadIdx.x;
  const int h = t >> 6, lane = t & 63;
  const int beg = offs[n], end = offs[n + 1];
  const float sn = sums[n * 4 + h];
  float acc0 = 0.f, acc1 = 0.f, acc2 = 0.f, acc3 = 0.f;
  int j = beg;
  for (; j + 3 < end; j += 4) {
#define LD(i)                                                              \
    const int d##i = drugA[j + i];                                         \
    const int o##i = otherA[j + i];                                        \
    const float e##i = esx[(j + i) * 4 + h];                               \
    const float p##i = __bfloat162float(proj0[(size_t)d##i * 256 + t]);    \
    const float so##i = sums[o##i * 4 + h];
    LD(0) LD(1) LD(2) LD(3)
#undef LD
    acc0 = fmaf(p0, e0 / (sn + so0 + 1e-16f), acc0);
    acc1 = fmaf(p1, e1 / (sn + so1 + 1e-16f), acc1);
    acc2 = fmaf(p2, e2 / (sn + so2 + 1e-16f), acc2);
    acc3 = fmaf(p3, e3 / (sn + so3 + 1e-16f), acc3);
  }
  for (; j < end; ++j) {
    const int d0 = drugA[j];
    const int o0 = otherA[j];
    const float e0 = esx[j * 4 + h];
    const float p0 = __bfloat162float(proj0[(size_t)d0 * 256 + t]);
    acc0 = fmaf(p0, e0 / (sn + sums[o0 * 4 + h] + 1e-16f), acc0);
  }
  const float acc = (acc0 + acc1) + (acc2 + acc3);
  const float v = acc + x[n * 64 + lane] + b0[t];
  const float hv = v > 0.f ? v : expm1f(v);
  out0b[(size_t)n * 256 + t] = __float2bfloat16(hv);
  float y1 = hv * c1[t], y2 = hv * c2[t], y3 = hv * c3[t];
#pragma unroll
  for (int off = 32; off > 0; off >>= 1) {
    y1 += __shfl_xor(y1, off, 64);
    y2 += __shfl_xor(y2, off, 64);
    y3 += __shfl_xor(y3, off, 64);
  }
  if (lane == 0) { red[h] = y1; red[4 + h] = y2; red[8 + h] = y3; }
  __syncthreads();
  if (t == 0) s1_1[n] = (red[0] + red[1]) + (red[2] + red[3]);
  else if (t == 1) s2_1[n] = (red[4] + red[5]) + (red[6] + red[7]);
  else if (t == 2) s3_1[n] = (red[8] + red[9]) + (red[10] + red[11]);
}

// ================= Weight prep for MFMA GEMM ==================================
// Bswz[((g*8+s)*64+l)*8+j] = Wc[col=16g+(l&15)][k=32s+(l>>4)*8+j], bf16.
// Wc rows 0..63 = W1, 64..127 = Wskip1.
__global__ void k_prepw(const float* __restrict__ W1,
                        const float* __restrict__ Wskip1,
                        __hip_bfloat16* __restrict__ Bswz) {
  const int t = blockIdx.x * 256 + threadIdx.x;  // < 32768
  const int j = t & 7, l = (t >> 3) & 63, s = (t >> 9) & 7, g = t >> 12;
  const int k = s * 32 + (l >> 4) * 8 + j;
  const int col = g * 16 + (l & 15);
  const float v = (col < 64) ? W1[col * 256 + k] : Wskip1[(col - 64) * 256 + k];
  Bswz[t] = __float2bfloat16(v);
}

// c{1,2,3}[k] = sum_f a{1,2,3}[f] * W1[f,k]
__global__ void k_prepc(const float* __restrict__ W1, const float* __restrict__ a1,
                        const float* __restrict__ a2, const float* __restrict__ a3,
                        float* __restrict__ c1, float* __restrict__ c2,
                        float* __restrict__ c3) {
  const int k = threadIdx.x;  // 256
  float x1 = 0.f, x2 = 0.f, x3 = 0.f;
  for (int f = 0; f < 64; ++f) {
    const float w = W1[f * 256 + k];
    x1 = fmaf(w, a1[f], x1);
    x2 = fmaf(w, a2[f], x2);
    x3 = fmaf(w, a3[f], x3);
  }
  c1[k] = x1; c2[k] = x2; c3[k] = x3;
}

// ================= Fused layer-1 MFMA GEMM: [M,256]x[256,128] =================
// cols 0..63 -> proj1 (bf16), cols 64..127 -> out (+b1, fp32).
#define MMROWS 64
#define LDA 264  // padded A-tile row stride (bf16 elems); 528 B, 16B-aligned
__global__ __launch_bounds__(256) void k_mm1(
    const __hip_bfloat16* __restrict__ hsrc, const short* __restrict__ Bswz,
    const float* __restrict__ b1, __hip_bfloat16* __restrict__ proj1,
    float* __restrict__ out) {
  __shared__ short As[MMROWS * LDA];
  const int t = threadIdx.x;
  const int lane = t & 63, w = t >> 6;
  const int base = blockIdx.x * MMROWS;
  // stage A tile: 64 rows x 256 bf16 (512 B/row), 16 B per thread-chunk
  for (int q = 0; q < 8; ++q) {
    const int i = q * 256 + t;     // 2048 chunks
    const int r = i >> 5;          // row 0..63
    const int c = (i & 31) * 8;    // elem 0..248
    int rg = base + r;
    if (rg >= NNODES) rg = NNODES - 1;  // clamp (dup read, stores guarded)
    const float4 v = *(const float4*)((const short*)hsrc + (size_t)rg * 256 + c);
    *(float4*)(&As[r * LDA + c]) = v;
  }
  __syncthreads();
  const short8* B8 = (const short8*)Bswz;
  f32x4 acc[8];
#pragma unroll
  for (int g = 0; g < 8; ++g) acc[g] = (f32x4){0.f, 0.f, 0.f, 0.f};
  const int aoff = (w * 16 + (lane & 15)) * LDA + (lane >> 4) * 8;
#pragma unroll
  for (int s = 0; s < 8; ++s) {
    const short8 af = *(const short8*)(&As[aoff + s * 32]);
#pragma unroll
    for (int g = 0; g < 8; ++g) {
      const short8 bf = B8[(g * 8 + s) * 64 + lane];
      acc[g] = __builtin_amdgcn_mfma_f32_16x16x32_bf16(af, bf, acc[g], 0, 0, 0);
    }
  }
  // epilogue: C/D layout col=lane&15, row=(lane>>4)*4+reg
  const int r0 = base + w * 16 + (lane >> 4) * 4;
  const int cn = lane & 15;
#pragma unroll
  for (int g = 0; g < 4; ++g) {
    const int col = g * 16 + cn;
#pragma unroll
    for (int r = 0; r < 4; ++r) {
      const int row = r0 + r;
      if (row < NNODES)
        proj1[(size_t)row * 64 + col] = __float2bfloat16(acc[g][r]);
    }
  }
#pragma unroll
  for (int g = 4; g < 8; ++g) {
    const int col = (g - 4) * 16 + cn;
    const float bv = b1[col];
#pragma unroll
    for (int r = 0; r < 4; ++r) {
      const int row = r0 + r;
      if (row < NNODES) out[(size_t)row * 64 + col] = acc[g][r] + bv;
    }
  }
}

// ================= Layer 1 attention ==========================================
__global__ void k_escore1(const int* __restrict__ ei, const float* __restrict__ s1,
                          const float* __restrict__ s2, const float* __restrict__ s3,
                          float* __restrict__ ebuf) {
  const int e = blockIdx.x * 256 + threadIdx.x;
  if (e >= NEDGES) return;
  float s = s1[ei[e]] + s2[ei[NEDGES + e]] + s3[ei[2 * NEDGES + e]];
  s = s > 0.f ? s : 0.2f * s;
  ebuf[e] = __expf(s);
}

__global__ void k_sums1(const int* __restrict__ offs, const int* __restrict__ eidxA,
                        const float* __restrict__ ebuf, float* __restrict__ sums) {
  const int n = blockIdx.x * 256 + threadIdx.x;
  if (n >= NNODES) return;
  const int beg = offs[n], end = offs[n + 1];
  float acc = 0.f;
  for (int j = beg; j < end; ++j) acc += ebuf[eidxA[j]];
  sums[n] = acc;
}

// ================= Layer 1 aggregate (fused att), wave per node ===============
__global__ __launch_bounds__(256) void k_agg1(
    const int* __restrict__ offs, const int* __restrict__ drugA,
    const int* __restrict__ otherA, const int* __restrict__ eidxA,
    const float* __restrict__ ebuf, const float* __restrict__ sums,
    const __hip_bfloat16* __restrict__ proj1, float* __restrict__ dout) {
  const int lane = threadIdx.x & 63, wid = threadIdx.x >> 6;
  const int n = blockIdx.x * 4 + wid;
  if (n >= NNODES) return;
  const int beg = offs[n], end = offs[n + 1];
  const float sn = sums[n];
  float acc0 = 0.f, acc1 = 0.f, acc2 = 0.f, acc3 = 0.f;
  int j = beg;
  for (; j + 3 < end; j += 4) {
#define LD(i)                                                              \
    const int d##i = drugA[j + i];                                         \
    const int o##i = otherA[j + i];                                        \
    const float e##i = ebuf[eidxA[j + i]];                                 \
    const float p##i = __bfloat162float(proj1[(size_t)d##i * 64 + lane]);  \
    const float so##i = sums[o##i];
    LD(0) LD(1) LD(2) LD(3)
#undef LD
    acc0 = fmaf(p0, e0 / (sn + so0 + 1e-16f), acc0);
    acc1 = fmaf(p1, e1 / (sn + so1 + 1e-16f), acc1);
    acc2 = fmaf(p2, e2 / (sn + so2 + 1e-16f), acc2);
    acc3 = fmaf(p3, e3 / (sn + so3 + 1e-16f), acc3);
  }
  for (; j < end; ++j) {
    const int d0 = drugA[j];
    const float e0 = ebuf[eidxA[j]];
    const float p0 = __bfloat162float(proj1[(size_t)d0 * 64 + lane]);
    acc0 = fmaf(p0, e0 / (sn + sums[otherA[j]] + 1e-16f), acc0);
  }
  dout[(size_t)n * 64 + lane] += (acc0 + acc1) + (acc2 + acc3);
}

extern "C" void kernel_launch(void* const* d_in, const int* in_sizes, int n_in,
                              void* d_out, int out_size, void* d_ws, size_t ws_size,
                              hipStream_t stream) {
  const float* x = (const float*)d_in[0];
  const int* ei = (const int*)d_in[1];
  const float* W0 = (const float*)d_in[2];
  const float* a10 = (const float*)d_in[3];
  const float* a20 = (const float*)d_in[4];
  const float* a30 = (const float*)d_in[5];
  // d_in[6] = Wskip0: unused (layer-0 skip is identity, F==DIN)
  const float* b0 = (const float*)d_in[7];
  const float* W1 = (const float*)d_in[8];
  const float* a11 = (const float*)d_in[9];
  const float* a21 = (const float*)d_in[10];
  const float* a31 = (const float*)d_in[11];
  const float* Wskip1 = (const float*)d_in[12];
  const float* b1 = (const float*)d_in[13];
  float* out = (float*)d_out;

  // ---- Workspace layout: ~141 MB ----
  __hip_bfloat16* P = (__hip_bfloat16*)d_ws;         // N*256 bf16 (proj0/proj1)
  __hip_bfloat16* out0b = P + (size_t)NNODES * 256;  // N*256 bf16 (h, layer-1 in)
  float* s1_0 = (float*)(out0b + (size_t)NNODES * 256);  // N*4 x3
  float* s2_0 = s1_0 + (size_t)NNODES * 4;
  float* s3_0 = s2_0 + (size_t)NNODES * 4;
  float* sums0 = s3_0 + (size_t)NNODES * 4;          // N*4
  float* esx0 = sums0 + (size_t)NNODES * 4;          // 2E*4 (float4/slot)
  int* drugA = (int*)(esx0 + (size_t)2 * NEDGES * 4);  // 2E
  int* otherA = drugA + 2 * NEDGES;                  // 2E
  int* eidxA = otherA + 2 * NEDGES;                  // 2E
  int* offs = eidxA + 2 * NEDGES;                    // N+1 (padded to N+16)
  float* s1_1 = (float*)(offs + NNODES + 16);        // N x3
  float* s2_1 = s1_1 + NNODES;
  float* s3_1 = s2_1 + NNODES;
  float* sums1 = s3_1 + NNODES;                      // N
  float* ebuf1 = sums1 + NNODES;                     // E
  __hip_bfloat16* Bswz = (__hip_bfloat16*)(ebuf1 + NEDGES);  // 32768 bf16
  float* c1 = (float*)(Bswz + 32768);                // 256 x3
  float* c2 = c1 + 256;
  float* c3 = c2 + 256;
  // CSR-build int scratch aliases out0b region (dead until k_agg0 writes it):
  int* deg = (int*)out0b;
  int* cursor = deg + NNODES;
  int* bsums = cursor + NNODES;

  __hip_bfloat16* proj0 = P;
  __hip_bfloat16* proj1 = P;  // aliases proj0 (dead after k_agg0)

  // ---- weight prep (independent of everything) ----
  k_prepw<<<128, 256, 0, stream>>>(W1, Wskip1, Bswz);
  k_prepc<<<1, 256, 0, stream>>>(W1, a11, a21, a31, c1, c2, c3);

  // ---- Layer 0 projection + scores (needed before CSR fill) ----
  k_proj0<<<NNODES / 32, 256, 0, stream>>>(x, W0, a10, a20, a30, proj0, s1_0,
                                           s2_0, s3_0);

  // ---- CSR build with slot records + layer-0 exp-scores ----
  hipMemsetAsync(deg, 0, NNODES * sizeof(int), stream);
  k_deg<<<(2 * NEDGES + 255) / 256, 256, 0, stream>>>(ei, deg);
  k_scan1<<<NB_SCAN, 256, 0, stream>>>(deg, offs, bsums);
  k_scan2<<<1, 512, 0, stream>>>(bsums);
  k_scan3<<<NB_SCAN, 256, 0, stream>>>(offs, bsums, cursor);
  k_fill2<<<(2 * NEDGES + 255) / 256, 256, 0, stream>>>(
      ei, cursor, s1_0, s2_0, s3_0, drugA, otherA, eidxA, esx0);

  // ---- Layer 0 aggregate (writes bf16 h + layer-1 scores) ----
  k_sums0<<<(NNODES + 255) / 256, 256, 0, stream>>>(offs, esx0, sums0);
  k_agg0<<<NNODES, 256, 0, stream>>>(offs, drugA, otherA, esx0, sums0, proj0, x,
                                     b0, c1, c2, c3, out0b, s1_1, s2_1, s3_1);

  // ---- Layer 1: fused MFMA GEMM (W1 ++ Wskip1), then attention ----
  k_mm1<<<(NNODES + MMROWS - 1) / MMROWS, 256, 0, stream>>>(
      out0b, (const short*)Bswz, b1, proj1, out);
  k_escore1<<<(NEDGES + 255) / 256, 256, 0, stream>>>(ei, s1_1, s2_1, s3_1, ebuf1);
  k_sums1<<<(NNODES + 255) / 256, 256, 0, stream>>>(offs, eidxA, ebuf1, sums1);
  k_agg1<<<(NNODES + 3) / 4, 256, 0, stream>>>(offs, drugA, otherA, eidxA, ebuf1,
                                               sums1, proj1, out);
}

// Round 6
// 698.988 us; speedup vs baseline: 3.0704x; 1.0191x over previous
//
#include <hip/hip_runtime.h>
#include <hip/hip_bf16.h>
#include <math.h>

#define NNODES 100000
#define NEDGES 500000
#define NB_SCAN 391  // ceil(NNODES/256)

typedef __attribute__((ext_vector_type(8))) short short8;
typedef __attribute__((ext_vector_type(4))) float f32x4;

// ================= CSR build ==================================================
__global__ void k_deg(const int* __restrict__ ei, int* __restrict__ deg) {
  const int idx = blockIdx.x * 256 + threadIdx.x;
  if (idx < 2 * NEDGES) atomicAdd(&deg[ei[NEDGES + idx]], 1);
}

__global__ void k_scan1(const int* __restrict__ deg, int* __restrict__ offs,
                        int* __restrict__ bsums) {
  __shared__ int sh[256];
  const int t = threadIdx.x;
  const int i = blockIdx.x * 256 + t;
  const int v = (i < NNODES) ? deg[i] : 0;
  sh[t] = v;
  __syncthreads();
  for (int d = 1; d < 256; d <<= 1) {
    const int add = (t >= d) ? sh[t - d] : 0;
    __syncthreads();
    sh[t] += add;
    __syncthreads();
  }
  if (i < NNODES) offs[i] = sh[t] - v;  // exclusive
  if (t == 255) bsums[blockIdx.x] = sh[255];
}

__global__ void k_scan2(int* __restrict__ bsums) {
  __shared__ int sh[512];
  const int t = threadIdx.x;
  const int v = (t < NB_SCAN) ? bsums[t] : 0;
  sh[t] = v;
  __syncthreads();
  for (int d = 1; d < 512; d <<= 1) {
    const int add = (t >= d) ? sh[t - d] : 0;
    __syncthreads();
    sh[t] += add;
    __syncthreads();
  }
  if (t < NB_SCAN) bsums[t] = sh[t] - v;  // exclusive
}

__global__ void k_scan3(int* __restrict__ offs, const int* __restrict__ bsums,
                        int* __restrict__ cursor) {
  const int i = blockIdx.x * 256 + threadIdx.x;
  if (i < NNODES) {
    const int o = offs[i] + bsums[blockIdx.x];
    offs[i] = o;
    cursor[i] = o;
  }
  if (i == 0) offs[NNODES] = 2 * NEDGES;
}

// Fill slot records: drug, other-receiver, edge id, and layer-0 exp-scores.
__global__ void k_fill2(const int* __restrict__ ei, int* __restrict__ cursor,
                        const float* __restrict__ s1, const float* __restrict__ s2,
                        const float* __restrict__ s3, int* __restrict__ drugA,
                        int* __restrict__ otherA, int* __restrict__ eidxA,
                        float* __restrict__ esx) {
  const int idx = blockIdx.x * 256 + threadIdx.x;
  if (idx >= 2 * NEDGES) return;
  const int n = ei[NEDGES + idx];  // this slot's receiver
  const int e = (idx < NEDGES) ? idx : idx - NEDGES;
  const int drug = ei[e], tgt = ei[NEDGES + e], dis = ei[2 * NEDGES + e];
  const int other = (idx < NEDGES) ? dis : tgt;
  const float4 A = ((const float4*)s1)[drug];
  const float4 B = ((const float4*)s2)[tgt];
  const float4 C = ((const float4*)s3)[dis];
  float4 r;
  float s;
  s = A.x + B.x + C.x; s = s > 0.f ? s : 0.2f * s; r.x = __expf(s);
  s = A.y + B.y + C.y; s = s > 0.f ? s : 0.2f * s; r.y = __expf(s);
  s = A.z + B.z + C.z; s = s > 0.f ? s : 0.2f * s; r.z = __expf(s);
  s = A.w + B.w + C.w; s = s > 0.f ? s : 0.2f * s; r.w = __expf(s);
  const int pos = atomicAdd(&cursor[n], 1);
  drugA[pos] = drug;
  otherA[pos] = other;
  eidxA[pos] = e;
  ((float4*)esx)[pos] = r;
}

// ================= Layer 0 projection (W0 in regs, uniform x loads) ===========
__global__ __launch_bounds__(256) void k_proj0(
    const float* __restrict__ x, const float* __restrict__ W0,
    const float* __restrict__ a1, const float* __restrict__ a2,
    const float* __restrict__ a3,
    __hip_bfloat16* __restrict__ proj0, float* __restrict__ s1,
    float* __restrict__ s2, float* __restrict__ s3) {
  const int t = threadIdx.x;
  const int base = blockIdx.x * 32;
  float w[64];
#pragma unroll
  for (int q = 0; q < 16; ++q) {
    float4 v = ((const float4*)W0)[t * 16 + q];
    w[q * 4 + 0] = v.x; w[q * 4 + 1] = v.y; w[q * 4 + 2] = v.z; w[q * 4 + 3] = v.w;
  }
  const float a1v = a1[t], a2v = a2[t], a3v = a3[t];
  const int lane = t & 63, head = t >> 6;
  for (int i = 0; i < 32; ++i) {
    const int node = base + i;
    const float4* xr = (const float4*)(x + (size_t)node * 64);
    float acc = 0.f;
#pragma unroll
    for (int q = 0; q < 16; ++q) {
      const float4 xv = xr[q];  // wave-uniform broadcast
      acc = fmaf(xv.x, w[q * 4 + 0], acc);
      acc = fmaf(xv.y, w[q * 4 + 1], acc);
      acc = fmaf(xv.z, w[q * 4 + 2], acc);
      acc = fmaf(xv.w, w[q * 4 + 3], acc);
    }
    proj0[(size_t)node * 256 + t] = __float2bfloat16(acc);
    float v1 = acc * a1v, v2 = acc * a2v, v3 = acc * a3v;
#pragma unroll
    for (int off = 32; off > 0; off >>= 1) {
      v1 += __shfl_xor(v1, off, 64);
      v2 += __shfl_xor(v2, off, 64);
      v3 += __shfl_xor(v3, off, 64);
    }
    if (lane == 0) {
      s1[node * 4 + head] = v1;
      s2[node * 4 + head] = v2;
      s3[node * 4 + head] = v3;
    }
  }
}

// ================= Layer 0 denominators: sequential segmented sum =============
__global__ void k_sums0(const int* __restrict__ offs, const float* __restrict__ esx,
                        float* __restrict__ sums) {
  const int n = blockIdx.x * 256 + threadIdx.x;
  if (n >= NNODES) return;
  const int beg = offs[n], end = offs[n + 1];
  float4 acc = make_float4(0.f, 0.f, 0.f, 0.f);
  for (int j = beg; j < end; ++j) {
    const float4 v = ((const float4*)esx)[j];
    acc.x += v.x; acc.y += v.y; acc.z += v.z; acc.w += v.w;
  }
  ((float4*)sums)[n] = acc;
}

// ========== Layer 0 attention: esx -> att in place (slot order) ===============
__global__ void k_att0(const int* __restrict__ offs, const int* __restrict__ otherA,
                       const float* __restrict__ sums, float* __restrict__ esx) {
  const int n = blockIdx.x * 256 + threadIdx.x;
  if (n >= NNODES) return;
  const int beg = offs[n], end = offs[n + 1];
  const float4 sn = ((const float4*)sums)[n];
  for (int j = beg; j < end; ++j) {
    const float4 so = ((const float4*)sums)[otherA[j]];
    float4 e = ((const float4*)esx)[j];
    e.x *= __builtin_amdgcn_rcpf(sn.x + so.x + 1e-16f);
    e.y *= __builtin_amdgcn_rcpf(sn.y + so.y + 1e-16f);
    e.z *= __builtin_amdgcn_rcpf(sn.z + so.z + 1e-16f);
    e.w *= __builtin_amdgcn_rcpf(sn.w + so.w + 1e-16f);
    ((float4*)esx)[j] = e;
  }
}

// ====== Layer 0 aggregate + skip + bias + elu; h -> bf16; layer-1 scores ======
// Block per node; thread t = (head h = t>>6, feature lane = t&63).
// Inner loop: pure gather+fma (att precomputed).
__global__ __launch_bounds__(256) void k_agg0(
    const int* __restrict__ offs, const int* __restrict__ drugA,
    const float* __restrict__ att, const __hip_bfloat16* __restrict__ proj0,
    const float* __restrict__ x, const float* __restrict__ b0,
    const float* __restrict__ c1, const float* __restrict__ c2,
    const float* __restrict__ c3, __hip_bfloat16* __restrict__ out0b,
    float* __restrict__ s1_1, float* __restrict__ s2_1,
    float* __restrict__ s3_1) {
  __shared__ float red[12];
  const int n = blockIdx.x;
  const int t = threadIdx.x;
  const int h = t >> 6, lane = t & 63;
  const int beg = offs[n], end = offs[n + 1];
  float acc0 = 0.f, acc1 = 0.f, acc2 = 0.f, acc3 = 0.f;
  int j = beg;
  for (; j + 3 < end; j += 4) {
#define LD(i)                                                              \
    const int d##i = drugA[j + i];                                         \
    const float a##i = att[(j + i) * 4 + h];                               \
    const float p##i = __bfloat162float(proj0[(unsigned)(d##i * 256 + t)]);
    LD(0) LD(1) LD(2) LD(3)
#undef LD
    acc0 = fmaf(p0, a0, acc0);
    acc1 = fmaf(p1, a1, acc1);
    acc2 = fmaf(p2, a2, acc2);
    acc3 = fmaf(p3, a3, acc3);
  }
  for (; j < end; ++j) {
    const int d0 = drugA[j];
    const float a0 = att[j * 4 + h];
    acc0 = fmaf(__bfloat162float(proj0[(unsigned)(d0 * 256 + t)]), a0, acc0);
  }
  const float acc = (acc0 + acc1) + (acc2 + acc3);
  const float v = acc + x[n * 64 + lane] + b0[t];
  const float hv = v > 0.f ? v : expm1f(v);
  out0b[(size_t)n * 256 + t] = __float2bfloat16(hv);
  float y1 = hv * c1[t], y2 = hv * c2[t], y3 = hv * c3[t];
#pragma unroll
  for (int off = 32; off > 0; off >>= 1) {
    y1 += __shfl_xor(y1, off, 64);
    y2 += __shfl_xor(y2, off, 64);
    y3 += __shfl_xor(y3, off, 64);
  }
  if (lane == 0) { red[h] = y1; red[4 + h] = y2; red[8 + h] = y3; }
  __syncthreads();
  if (t == 0) s1_1[n] = (red[0] + red[1]) + (red[2] + red[3]);
  else if (t == 1) s2_1[n] = (red[4] + red[5]) + (red[6] + red[7]);
  else if (t == 2) s3_1[n] = (red[8] + red[9]) + (red[10] + red[11]);
}

// ================= Weight prep for MFMA GEMM ==================================
// Bswz[((g*8+s)*64+l)*8+j] = Wc[col=16g+(l&15)][k=32s+(l>>4)*8+j], bf16.
// Wc rows 0..63 = W1, 64..127 = Wskip1.
__global__ void k_prepw(const float* __restrict__ W1,
                        const float* __restrict__ Wskip1,
                        __hip_bfloat16* __restrict__ Bswz) {
  const int t = blockIdx.x * 256 + threadIdx.x;  // < 32768
  const int j = t & 7, l = (t >> 3) & 63, s = (t >> 9) & 7, g = t >> 12;
  const int k = s * 32 + (l >> 4) * 8 + j;
  const int col = g * 16 + (l & 15);
  const float v = (col < 64) ? W1[col * 256 + k] : Wskip1[(col - 64) * 256 + k];
  Bswz[t] = __float2bfloat16(v);
}

// c{1,2,3}[k] = sum_f a{1,2,3}[f] * W1[f,k]
__global__ void k_prepc(const float* __restrict__ W1, const float* __restrict__ a1,
                        const float* __restrict__ a2, const float* __restrict__ a3,
                        float* __restrict__ c1, float* __restrict__ c2,
                        float* __restrict__ c3) {
  const int k = threadIdx.x;  // 256
  float x1 = 0.f, x2 = 0.f, x3 = 0.f;
  for (int f = 0; f < 64; ++f) {
    const float w = W1[f * 256 + k];
    x1 = fmaf(w, a1[f], x1);
    x2 = fmaf(w, a2[f], x2);
    x3 = fmaf(w, a3[f], x3);
  }
  c1[k] = x1; c2[k] = x2; c3[k] = x3;
}

// ================= Fused layer-1 MFMA GEMM: [M,256]x[256,128] =================
// cols 0..63 -> proj1 (bf16), cols 64..127 -> out (+b1, fp32).
#define MMROWS 64
#define LDA 264  // padded A-tile row stride (bf16 elems); 528 B, 16B-aligned
__global__ __launch_bounds__(256) void k_mm1(
    const __hip_bfloat16* __restrict__ hsrc, const short* __restrict__ Bswz,
    const float* __restrict__ b1, __hip_bfloat16* __restrict__ proj1,
    float* __restrict__ out) {
  __shared__ short As[MMROWS * LDA];
  const int t = threadIdx.x;
  const int lane = t & 63, w = t >> 6;
  const int base = blockIdx.x * MMROWS;
  // stage A tile: 64 rows x 256 bf16 (512 B/row), 16 B per thread-chunk
  for (int q = 0; q < 8; ++q) {
    const int i = q * 256 + t;     // 2048 chunks
    const int r = i >> 5;          // row 0..63
    const int c = (i & 31) * 8;    // elem 0..248
    int rg = base + r;
    if (rg >= NNODES) rg = NNODES - 1;  // clamp (dup read, stores guarded)
    const float4 v = *(const float4*)((const short*)hsrc + (size_t)rg * 256 + c);
    *(float4*)(&As[r * LDA + c]) = v;
  }
  __syncthreads();
  const short8* B8 = (const short8*)Bswz;
  f32x4 acc[8];
#pragma unroll
  for (int g = 0; g < 8; ++g) acc[g] = (f32x4){0.f, 0.f, 0.f, 0.f};
  const int aoff = (w * 16 + (lane & 15)) * LDA + (lane >> 4) * 8;
#pragma unroll
  for (int s = 0; s < 8; ++s) {
    const short8 af = *(const short8*)(&As[aoff + s * 32]);
#pragma unroll
    for (int g = 0; g < 8; ++g) {
      const short8 bf = B8[(g * 8 + s) * 64 + lane];
      acc[g] = __builtin_amdgcn_mfma_f32_16x16x32_bf16(af, bf, acc[g], 0, 0, 0);
    }
  }
  // epilogue: C/D layout col=lane&15, row=(lane>>4)*4+reg
  const int r0 = base + w * 16 + (lane >> 4) * 4;
  const int cn = lane & 15;
#pragma unroll
  for (int g = 0; g < 4; ++g) {
    const int col = g * 16 + cn;
#pragma unroll
    for (int r = 0; r < 4; ++r) {
      const int row = r0 + r;
      if (row < NNODES)
        proj1[(size_t)row * 64 + col] = __float2bfloat16(acc[g][r]);
    }
  }
#pragma unroll
  for (int g = 4; g < 8; ++g) {
    const int col = (g - 4) * 16 + cn;
    const float bv = b1[col];
#pragma unroll
    for (int r = 0; r < 4; ++r) {
      const int row = r0 + r;
      if (row < NNODES) out[(size_t)row * 64 + col] = acc[g][r] + bv;
    }
  }
}

// ================= Layer 1 attention ==========================================
__global__ void k_escore1(const int* __restrict__ ei, const float* __restrict__ s1,
                          const float* __restrict__ s2, const float* __restrict__ s3,
                          float* __restrict__ ebuf) {
  const int e = blockIdx.x * 256 + threadIdx.x;
  if (e >= NEDGES) return;
  float s = s1[ei[e]] + s2[ei[NEDGES + e]] + s3[ei[2 * NEDGES + e]];
  s = s > 0.f ? s : 0.2f * s;
  ebuf[e] = __expf(s);
}

__global__ void k_sums1(const int* __restrict__ offs, const int* __restrict__ eidxA,
                        const float* __restrict__ ebuf, float* __restrict__ sums) {
  const int n = blockIdx.x * 256 + threadIdx.x;
  if (n >= NNODES) return;
  const int beg = offs[n], end = offs[n + 1];
  float acc = 0.f;
  for (int j = beg; j < end; ++j) acc += ebuf[eidxA[j]];
  sums[n] = acc;
}

// ========== Layer 1 attention per slot (node order) ===========================
__global__ void k_att1(const int* __restrict__ offs, const int* __restrict__ otherA,
                       const int* __restrict__ eidxA, const float* __restrict__ ebuf,
                       const float* __restrict__ sums, float* __restrict__ att1s) {
  const int n = blockIdx.x * 256 + threadIdx.x;
  if (n >= NNODES) return;
  const int beg = offs[n], end = offs[n + 1];
  const float sn = sums[n];
  for (int j = beg; j < end; ++j) {
    const float e = ebuf[eidxA[j]];
    const float so = sums[otherA[j]];
    att1s[j] = e * __builtin_amdgcn_rcpf(sn + so + 1e-16f);
  }
}

// ================= Layer 1 aggregate, wave per node ===========================
__global__ __launch_bounds__(256) void k_agg1(
    const int* __restrict__ offs, const int* __restrict__ drugA,
    const float* __restrict__ att1s, const __hip_bfloat16* __restrict__ proj1,
    float* __restrict__ dout) {
  const int lane = threadIdx.x & 63, wid = threadIdx.x >> 6;
  const int n = blockIdx.x * 4 + wid;
  if (n >= NNODES) return;
  const int beg = offs[n], end = offs[n + 1];
  float acc0 = 0.f, acc1 = 0.f, acc2 = 0.f, acc3 = 0.f;
  int j = beg;
  for (; j + 3 < end; j += 4) {
#define LD(i)                                                              \
    const int d##i = drugA[j + i];                                         \
    const float a##i = att1s[j + i];                                       \
    const float p##i = __bfloat162float(proj1[(unsigned)(d##i * 64 + lane)]);
    LD(0) LD(1) LD(2) LD(3)
#undef LD
    acc0 = fmaf(p0, a0, acc0);
    acc1 = fmaf(p1, a1, acc1);
    acc2 = fmaf(p2, a2, acc2);
    acc3 = fmaf(p3, a3, acc3);
  }
  for (; j < end; ++j) {
    const int d0 = drugA[j];
    acc0 = fmaf(__bfloat162float(proj1[(unsigned)(d0 * 64 + lane)]), att1s[j],
                acc0);
  }
  dout[(size_t)n * 64 + lane] += (acc0 + acc1) + (acc2 + acc3);
}

extern "C" void kernel_launch(void* const* d_in, const int* in_sizes, int n_in,
                              void* d_out, int out_size, void* d_ws, size_t ws_size,
                              hipStream_t stream) {
  const float* x = (const float*)d_in[0];
  const int* ei = (const int*)d_in[1];
  const float* W0 = (const float*)d_in[2];
  const float* a10 = (const float*)d_in[3];
  const float* a20 = (const float*)d_in[4];
  const float* a30 = (const float*)d_in[5];
  // d_in[6] = Wskip0: unused (layer-0 skip is identity, F==DIN)
  const float* b0 = (const float*)d_in[7];
  const float* W1 = (const float*)d_in[8];
  const float* a11 = (const float*)d_in[9];
  const float* a21 = (const float*)d_in[10];
  const float* a31 = (const float*)d_in[11];
  const float* Wskip1 = (const float*)d_in[12];
  const float* b1 = (const float*)d_in[13];
  float* out = (float*)d_out;

  // ---- Workspace layout: ~141 MB ----
  __hip_bfloat16* P = (__hip_bfloat16*)d_ws;         // N*256 bf16 (proj0/proj1)
  __hip_bfloat16* out0b = P + (size_t)NNODES * 256;  // N*256 bf16 (h, layer-1 in)
  float* s1_0 = (float*)(out0b + (size_t)NNODES * 256);  // N*4 x3
  float* s2_0 = s1_0 + (size_t)NNODES * 4;
  float* s3_0 = s2_0 + (size_t)NNODES * 4;
  float* sums0 = s3_0 + (size_t)NNODES * 4;          // N*4
  float* esx0 = sums0 + (size_t)NNODES * 4;          // 2E*4 (float4/slot)
  int* drugA = (int*)(esx0 + (size_t)2 * NEDGES * 4);  // 2E
  int* otherA = drugA + 2 * NEDGES;                  // 2E
  int* eidxA = otherA + 2 * NEDGES;                  // 2E
  int* offs = eidxA + 2 * NEDGES;                    // N+1 (padded to N+16)
  float* s1_1 = (float*)(offs + NNODES + 16);        // N x3
  float* s2_1 = s1_1 + NNODES;
  float* s3_1 = s2_1 + NNODES;
  float* sums1 = s3_1 + NNODES;                      // N
  float* ebuf1 = sums1 + NNODES;                     // E
  __hip_bfloat16* Bswz = (__hip_bfloat16*)(ebuf1 + NEDGES);  // 32768 bf16
  float* c1 = (float*)(Bswz + 32768);                // 256 x3
  float* c2 = c1 + 256;
  float* c3 = c2 + 256;
  // CSR-build int scratch aliases out0b region (dead until k_agg0 writes it):
  int* deg = (int*)out0b;
  int* cursor = deg + NNODES;
  int* bsums = cursor + NNODES;

  __hip_bfloat16* proj0 = P;
  __hip_bfloat16* proj1 = P;   // aliases proj0 (dead after k_agg0)
  float* att1s = esx0;         // layer-1 per-slot att (esx0 dead after k_agg0)

  // ---- weight prep (independent of everything) ----
  k_prepw<<<128, 256, 0, stream>>>(W1, Wskip1, Bswz);
  k_prepc<<<1, 256, 0, stream>>>(W1, a11, a21, a31, c1, c2, c3);

  // ---- Layer 0 projection + scores (needed before CSR fill) ----
  k_proj0<<<NNODES / 32, 256, 0, stream>>>(x, W0, a10, a20, a30, proj0, s1_0,
                                           s2_0, s3_0);

  // ---- CSR build with slot records + layer-0 exp-scores ----
  hipMemsetAsync(deg, 0, NNODES * sizeof(int), stream);
  k_deg<<<(2 * NEDGES + 255) / 256, 256, 0, stream>>>(ei, deg);
  k_scan1<<<NB_SCAN, 256, 0, stream>>>(deg, offs, bsums);
  k_scan2<<<1, 512, 0, stream>>>(bsums);
  k_scan3<<<NB_SCAN, 256, 0, stream>>>(offs, bsums, cursor);
  k_fill2<<<(2 * NEDGES + 255) / 256, 256, 0, stream>>>(
      ei, cursor, s1_0, s2_0, s3_0, drugA, otherA, eidxA, esx0);

  // ---- Layer 0: sums -> att (in place) -> aggregate ----
  k_sums0<<<(NNODES + 255) / 256, 256, 0, stream>>>(offs, esx0, sums0);
  k_att0<<<(NNODES + 255) / 256, 256, 0, stream>>>(offs, otherA, sums0, esx0);
  k_agg0<<<NNODES, 256, 0, stream>>>(offs, drugA, esx0, proj0, x, b0, c1, c2,
                                     c3, out0b, s1_1, s2_1, s3_1);

  // ---- Layer 1: fused MFMA GEMM (W1 ++ Wskip1), then attention ----
  k_mm1<<<(NNODES + MMROWS - 1) / MMROWS, 256, 0, stream>>>(
      out0b, (const short*)Bswz, b1, proj1, out);
  k_escore1<<<(NEDGES + 255) / 256, 256, 0, stream>>>(ei, s1_1, s2_1, s3_1, ebuf1);
  k_sums1<<<(NNODES + 255) / 256, 256, 0, stream>>>(offs, eidxA, ebuf1, sums1);
  k_att1<<<(NNODES + 255) / 256, 256, 0, stream>>>(offs, otherA, eidxA, ebuf1,
                                                   sums1, att1s);
  k_agg1<<<(NNODES + 3) / 4, 256, 0, stream>>>(offs, drugA, att1s, proj1, out);
}

// Round 7
// 551.749 us; speedup vs baseline: 3.8898x; 1.2669x over previous
//
#include <hip/hip_runtime.h>
#include <hip/hip_bf16.h>
#include <math.h>

#define NNODES 100000
#define NEDGES 500000
#define NB_SCAN 391  // ceil(NNODES/256)

typedef __attribute__((ext_vector_type(8))) short short8;
typedef __attribute__((ext_vector_type(4))) float f32x4;

__device__ __forceinline__ float bf2f(__hip_bfloat16 v) {
  return __bfloat162float(v);
}

// ================= CSR build ==================================================
__global__ void k_deg(const int* __restrict__ ei, int* __restrict__ deg) {
  const int idx = blockIdx.x * 256 + threadIdx.x;
  if (idx < 2 * NEDGES) atomicAdd(&deg[ei[NEDGES + idx]], 1);
}

__global__ void k_scan1(const int* __restrict__ deg, int* __restrict__ offs,
                        int* __restrict__ bsums) {
  __shared__ int sh[256];
  const int t = threadIdx.x;
  const int i = blockIdx.x * 256 + t;
  const int v = (i < NNODES) ? deg[i] : 0;
  sh[t] = v;
  __syncthreads();
  for (int d = 1; d < 256; d <<= 1) {
    const int add = (t >= d) ? sh[t - d] : 0;
    __syncthreads();
    sh[t] += add;
    __syncthreads();
  }
  if (i < NNODES) offs[i] = sh[t] - v;  // exclusive
  if (t == 255) bsums[blockIdx.x] = sh[255];
}

__global__ void k_scan2(int* __restrict__ bsums) {
  __shared__ int sh[512];
  const int t = threadIdx.x;
  const int v = (t < NB_SCAN) ? bsums[t] : 0;
  sh[t] = v;
  __syncthreads();
  for (int d = 1; d < 512; d <<= 1) {
    const int add = (t >= d) ? sh[t - d] : 0;
    __syncthreads();
    sh[t] += add;
    __syncthreads();
  }
  if (t < NB_SCAN) bsums[t] = sh[t] - v;  // exclusive
}

__global__ void k_scan3(int* __restrict__ offs, const int* __restrict__ bsums,
                        int* __restrict__ cursor) {
  const int i = blockIdx.x * 256 + threadIdx.x;
  if (i < NNODES) {
    const int o = offs[i] + bsums[blockIdx.x];
    offs[i] = o;
    cursor[i] = o;
  }
  if (i == 0) offs[NNODES] = 2 * NEDGES;
}

// Fill slot records: drug id + (other-receiver | role<<30).
// role 0: receiver is tgt (other=dis); role 1: receiver is dis (other=tgt).
__global__ void k_fill3(const int* __restrict__ ei, int* __restrict__ cursor,
                        int* __restrict__ drugA, int* __restrict__ otherRole) {
  const int idx = blockIdx.x * 256 + threadIdx.x;
  if (idx >= 2 * NEDGES) return;
  const int n = ei[NEDGES + idx];
  const int e = (idx < NEDGES) ? idx : idx - NEDGES;
  const int drug = ei[e];
  const int other = (idx < NEDGES) ? ei[2 * NEDGES + e] : ei[NEDGES + e];
  const int role = (idx < NEDGES) ? 0 : 1;
  const int pos = atomicAdd(&cursor[n], 1);
  drugA[pos] = drug;
  otherRole[pos] = other | (role << 30);
}

// ========== B-matrix prep for layer-0 MFMA GEMM (K=64, 272 cols) ==============
// cols 0..255 = W0 (proj); 256..259 = a1^T-fold; 260..263 = a2; 264..267 = a3.
// Bswz[((g*2+s)*64+l)*8+j] = B[k=32s+(l>>4)*8+j][col=16g+(l&15)]
__global__ void k_prep0(const float* __restrict__ W0, const float* __restrict__ a1,
                        const float* __restrict__ a2, const float* __restrict__ a3,
                        __hip_bfloat16* __restrict__ B0) {
  const int t = blockIdx.x * 256 + threadIdx.x;  // < 17408
  const int j = t & 7, l = (t >> 3) & 63, s = (t >> 9) & 1, g = t >> 10;
  const int k = s * 32 + ((l >> 4) << 3) + j;
  const int col = g * 16 + (l & 15);
  float v = 0.f;
  if (col < 256) {
    v = W0[col * 64 + k];
  } else if (col < 268) {
    const int idx = col - 256;
    const int r = idx >> 2, h = idx & 3;
    const float* av = (r == 0) ? a1 : (r == 1) ? a2 : a3;
    for (int f = 0; f < 64; ++f)
      v = fmaf(av[h * 64 + f], W0[(h * 64 + f) * 64 + k], v);
  }
  B0[t] = __float2bfloat16(v);
}

// ========== B-matrix prep for layer-1 MFMA GEMM (K=256, 144 cols) =============
// cols 0..63 = W1; 64..127 = Wskip1; 128..130 = c1,c2,c3 (a^T W1 folds).
__global__ void k_prepw1(const float* __restrict__ W1,
                         const float* __restrict__ Wskip1,
                         const float* __restrict__ a1, const float* __restrict__ a2,
                         const float* __restrict__ a3,
                         __hip_bfloat16* __restrict__ B1) {
  const int t = blockIdx.x * 256 + threadIdx.x;  // < 36864
  const int j = t & 7, l = (t >> 3) & 63, s = (t >> 9) & 7, g = t >> 12;
  const int k = s * 32 + ((l >> 4) << 3) + j;
  const int col = g * 16 + (l & 15);
  float v = 0.f;
  if (col < 64) {
    v = W1[col * 256 + k];
  } else if (col < 128) {
    v = Wskip1[(col - 64) * 256 + k];
  } else if (col < 131) {
    const int r = col - 128;
    const float* av = (r == 0) ? a1 : (r == 1) ? a2 : a3;
    for (int f = 0; f < 64; ++f) v = fmaf(av[f], W1[f * 256 + k], v);
  }
  B1[t] = __float2bfloat16(v);
}

// ================= Layer-0 MFMA GEMM: [N,64] x [64,272] =======================
// cols 0..255 -> proj0 bf16; 256..267 -> s1_0/s2_0/s3_0 fp32.
#define LDA0 72  // shorts; 144 B row stride (16B-aligned)
__global__ __launch_bounds__(256) void k_mm0(
    const float* __restrict__ x, const short* __restrict__ B0,
    __hip_bfloat16* __restrict__ proj0, float* __restrict__ s1,
    float* __restrict__ s2, float* __restrict__ s3) {
  __shared__ __hip_bfloat16 As[64 * LDA0];
  const int t = threadIdx.x;
  const int lane = t & 63, w = t >> 6;
  const int base = blockIdx.x * 64;
  for (int q = 0; q < 4; ++q) {
    const int i = q * 256 + t;    // 1024 float4 chunks
    const int r = i >> 4;
    const int c4 = i & 15;
    int rg = base + r;
    if (rg >= NNODES) rg = NNODES - 1;
    const float4 v = ((const float4*)(x + (size_t)rg * 64))[c4];
    __hip_bfloat16* dst = &As[r * LDA0 + c4 * 4];
    dst[0] = __float2bfloat16(v.x);
    dst[1] = __float2bfloat16(v.y);
    dst[2] = __float2bfloat16(v.z);
    dst[3] = __float2bfloat16(v.w);
  }
  __syncthreads();
  const short8* B8 = (const short8*)B0;
  f32x4 acc[17];
#pragma unroll
  for (int g = 0; g < 17; ++g) acc[g] = (f32x4){0.f, 0.f, 0.f, 0.f};
  const int aoff = (w * 16 + (lane & 15)) * LDA0 + (lane >> 4) * 8;
#pragma unroll
  for (int s = 0; s < 2; ++s) {
    const short8 af = *(const short8*)(&As[aoff + s * 32]);
#pragma unroll
    for (int g = 0; g < 17; ++g) {
      const short8 bf = B8[(g * 2 + s) * 64 + lane];
      acc[g] = __builtin_amdgcn_mfma_f32_16x16x32_bf16(af, bf, acc[g], 0, 0, 0);
    }
  }
  const int r0 = base + w * 16 + (lane >> 4) * 4;
  const int cn = lane & 15;
#pragma unroll
  for (int g = 0; g < 16; ++g) {
    const int col = g * 16 + cn;
#pragma unroll
    for (int r = 0; r < 4; ++r) {
      const int row = r0 + r;
      if (row < NNODES)
        proj0[(size_t)row * 256 + col] = __float2bfloat16(acc[g][r]);
    }
  }
#pragma unroll
  for (int r = 0; r < 4; ++r) {
    const int row = r0 + r;
    if (row < NNODES) {
      if (cn < 4) s1[row * 4 + cn] = acc[16][r];
      else if (cn < 8) s2[row * 4 + (cn - 4)] = acc[16][r];
      else if (cn < 12) s3[row * 4 + (cn - 8)] = acc[16][r];
    }
  }
}

// ====== Layer-0 exp-scores per slot (node order) + denominator sums ===========
__global__ void k_sums0x(const int* __restrict__ offs, const int* __restrict__ drugA,
                         const int* __restrict__ otherRole,
                         const float* __restrict__ s1, const float* __restrict__ s2,
                         const float* __restrict__ s3, float* __restrict__ esx,
                         float* __restrict__ sums) {
  const int n = blockIdx.x * 256 + threadIdx.x;
  if (n >= NNODES) return;
  const int beg = offs[n], end = offs[n + 1];
  const float4 s2n = ((const float4*)s2)[n];
  const float4 s3n = ((const float4*)s3)[n];
  float4 acc = make_float4(0.f, 0.f, 0.f, 0.f);
  for (int j = beg; j < end; ++j) {
    const int d = drugA[j];
    const int orv = otherRole[j];
    const int o = orv & 0x3FFFFFFF;
    const int role = orv >> 30;
    const float4 A = ((const float4*)s1)[d];
    const float4 O = role ? ((const float4*)s2)[o] : ((const float4*)s3)[o];
    float4 S;
    if (role) S = s3n; else S = s2n;
    float4 es;
    float s;
    s = A.x + O.x + S.x; s = s > 0.f ? s : 0.2f * s; es.x = __expf(s);
    s = A.y + O.y + S.y; s = s > 0.f ? s : 0.2f * s; es.y = __expf(s);
    s = A.z + O.z + S.z; s = s > 0.f ? s : 0.2f * s; es.z = __expf(s);
    s = A.w + O.w + S.w; s = s > 0.f ? s : 0.2f * s; es.w = __expf(s);
    ((float4*)esx)[j] = es;
    acc.x += es.x; acc.y += es.y; acc.z += es.z; acc.w += es.w;
  }
  ((float4*)sums)[n] = acc;
}

// ========== Layer-0 attention: esx -> att in place (slot order) ===============
__global__ void k_att0(const int* __restrict__ offs, const int* __restrict__ otherRole,
                       const float* __restrict__ sums, float* __restrict__ esx) {
  const int n = blockIdx.x * 256 + threadIdx.x;
  if (n >= NNODES) return;
  const int beg = offs[n], end = offs[n + 1];
  const float4 sn = ((const float4*)sums)[n];
  for (int j = beg; j < end; ++j) {
    const float4 so = ((const float4*)sums)[otherRole[j] & 0x3FFFFFFF];
    float4 e = ((const float4*)esx)[j];
    e.x *= __builtin_amdgcn_rcpf(sn.x + so.x + 1e-16f);
    e.y *= __builtin_amdgcn_rcpf(sn.y + so.y + 1e-16f);
    e.z *= __builtin_amdgcn_rcpf(sn.z + so.z + 1e-16f);
    e.w *= __builtin_amdgcn_rcpf(sn.w + so.w + 1e-16f);
    ((float4*)esx)[j] = e;
  }
}

// ====== Layer-0 aggregate: wave per node (all 4 heads), skip+bias+elu =========
// lane = feature within head; heads handled as 4 accumulators.
__global__ __launch_bounds__(256) void k_agg0w(
    const int* __restrict__ offs, const int* __restrict__ drugA,
    const float* __restrict__ att, const __hip_bfloat16* __restrict__ proj0,
    const float* __restrict__ x, const float* __restrict__ b0,
    __hip_bfloat16* __restrict__ out0b) {
  const int lane = threadIdx.x & 63, wid = threadIdx.x >> 6;
  const int n = blockIdx.x * 4 + wid;
  if (n >= NNODES) return;
  const int beg = offs[n], end = offs[n + 1];
  float a0 = 0.f, a1 = 0.f, a2 = 0.f, a3 = 0.f;
  int j = beg;
  for (; j + 1 < end; j += 2) {
    const int dA = drugA[j], dB = drugA[j + 1];
    const float4 tA = ((const float4*)att)[j];
    const float4 tB = ((const float4*)att)[j + 1];
    const __hip_bfloat16* rA = proj0 + (size_t)dA * 256 + lane;
    const __hip_bfloat16* rB = proj0 + (size_t)dB * 256 + lane;
    const float pA0 = bf2f(rA[0]), pA1 = bf2f(rA[64]);
    const float pA2 = bf2f(rA[128]), pA3 = bf2f(rA[192]);
    const float pB0 = bf2f(rB[0]), pB1 = bf2f(rB[64]);
    const float pB2 = bf2f(rB[128]), pB3 = bf2f(rB[192]);
    a0 = fmaf(pA0, tA.x, a0); a1 = fmaf(pA1, tA.y, a1);
    a2 = fmaf(pA2, tA.z, a2); a3 = fmaf(pA3, tA.w, a3);
    a0 = fmaf(pB0, tB.x, a0); a1 = fmaf(pB1, tB.y, a1);
    a2 = fmaf(pB2, tB.z, a2); a3 = fmaf(pB3, tB.w, a3);
  }
  if (j < end) {
    const int dA = drugA[j];
    const float4 tA = ((const float4*)att)[j];
    const __hip_bfloat16* rA = proj0 + (size_t)dA * 256 + lane;
    a0 = fmaf(bf2f(rA[0]), tA.x, a0);
    a1 = fmaf(bf2f(rA[64]), tA.y, a1);
    a2 = fmaf(bf2f(rA[128]), tA.z, a2);
    a3 = fmaf(bf2f(rA[192]), tA.w, a3);
  }
  const float xs = x[n * 64 + lane];
  float v0 = a0 + xs + b0[lane];
  float v1 = a1 + xs + b0[64 + lane];
  float v2 = a2 + xs + b0[128 + lane];
  float v3 = a3 + xs + b0[192 + lane];
  v0 = v0 > 0.f ? v0 : expm1f(v0);
  v1 = v1 > 0.f ? v1 : expm1f(v1);
  v2 = v2 > 0.f ? v2 : expm1f(v2);
  v3 = v3 > 0.f ? v3 : expm1f(v3);
  __hip_bfloat16* orow = out0b + (size_t)n * 256 + lane;
  orow[0] = __float2bfloat16(v0);
  orow[64] = __float2bfloat16(v1);
  orow[128] = __float2bfloat16(v2);
  orow[192] = __float2bfloat16(v3);
}

// ====== Layer-1 MFMA GEMM: [N,256] x [256,144] ================================
// cols 0..63 -> proj1 bf16; 64..127 -> out (+b1) fp32; 128..130 -> s*_1 fp32.
#define LDA1 264  // shorts; 528 B (16B-aligned)
__global__ __launch_bounds__(256) void k_mm1(
    const __hip_bfloat16* __restrict__ hsrc, const short* __restrict__ B1,
    const float* __restrict__ b1, __hip_bfloat16* __restrict__ proj1,
    float* __restrict__ out, float* __restrict__ s1, float* __restrict__ s2,
    float* __restrict__ s3) {
  __shared__ short As[64 * LDA1];
  const int t = threadIdx.x;
  const int lane = t & 63, w = t >> 6;
  const int base = blockIdx.x * 64;
  for (int q = 0; q < 8; ++q) {
    const int i = q * 256 + t;
    const int r = i >> 5;
    const int c = (i & 31) * 8;
    int rg = base + r;
    if (rg >= NNODES) rg = NNODES - 1;
    const float4 v = *(const float4*)((const short*)hsrc + (size_t)rg * 256 + c);
    *(float4*)(&As[r * LDA1 + c]) = v;
  }
  __syncthreads();
  const short8* B8 = (const short8*)B1;
  f32x4 acc[9];
#pragma unroll
  for (int g = 0; g < 9; ++g) acc[g] = (f32x4){0.f, 0.f, 0.f, 0.f};
  const int aoff = (w * 16 + (lane & 15)) * LDA1 + (lane >> 4) * 8;
#pragma unroll
  for (int s = 0; s < 8; ++s) {
    const short8 af = *(const short8*)(&As[aoff + s * 32]);
#pragma unroll
    for (int g = 0; g < 9; ++g) {
      const short8 bf = B8[(g * 8 + s) * 64 + lane];
      acc[g] = __builtin_amdgcn_mfma_f32_16x16x32_bf16(af, bf, acc[g], 0, 0, 0);
    }
  }
  const int r0 = base + w * 16 + (lane >> 4) * 4;
  const int cn = lane & 15;
#pragma unroll
  for (int g = 0; g < 4; ++g) {
    const int col = g * 16 + cn;
#pragma unroll
    for (int r = 0; r < 4; ++r) {
      const int row = r0 + r;
      if (row < NNODES)
        proj1[(size_t)row * 64 + col] = __float2bfloat16(acc[g][r]);
    }
  }
#pragma unroll
  for (int g = 4; g < 8; ++g) {
    const int col = (g - 4) * 16 + cn;
    const float bv = b1[col];
#pragma unroll
    for (int r = 0; r < 4; ++r) {
      const int row = r0 + r;
      if (row < NNODES) out[(size_t)row * 64 + col] = acc[g][r] + bv;
    }
  }
#pragma unroll
  for (int r = 0; r < 4; ++r) {
    const int row = r0 + r;
    if (row < NNODES) {
      if (cn == 0) s1[row] = acc[8][r];
      else if (cn == 1) s2[row] = acc[8][r];
      else if (cn == 2) s3[row] = acc[8][r];
    }
  }
}

// ====== Layer-1 exp-scores per slot + denominator sums ========================
__global__ void k_sums1x(const int* __restrict__ offs, const int* __restrict__ drugA,
                         const int* __restrict__ otherRole,
                         const float* __restrict__ s1, const float* __restrict__ s2,
                         const float* __restrict__ s3, float* __restrict__ es1,
                         float* __restrict__ sums) {
  const int n = blockIdx.x * 256 + threadIdx.x;
  if (n >= NNODES) return;
  const int beg = offs[n], end = offs[n + 1];
  const float s2n = s2[n], s3n = s3[n];
  float acc = 0.f;
  for (int j = beg; j < end; ++j) {
    const int d = drugA[j];
    const int orv = otherRole[j];
    const int o = orv & 0x3FFFFFFF;
    const int role = orv >> 30;
    const float ov = role ? s2[o] : s3[o];
    const float sv = role ? s3n : s2n;
    float s = s1[d] + ov + sv;
    s = s > 0.f ? s : 0.2f * s;
    const float e = __expf(s);
    es1[j] = e;
    acc += e;
  }
  sums[n] = acc;
}

// ========== Layer-1 attention in place ========================================
__global__ void k_att1(const int* __restrict__ offs, const int* __restrict__ otherRole,
                       const float* __restrict__ sums, float* __restrict__ es1) {
  const int n = blockIdx.x * 256 + threadIdx.x;
  if (n >= NNODES) return;
  const int beg = offs[n], end = offs[n + 1];
  const float sn = sums[n];
  for (int j = beg; j < end; ++j) {
    const float so = sums[otherRole[j] & 0x3FFFFFFF];
    es1[j] *= __builtin_amdgcn_rcpf(sn + so + 1e-16f);
  }
}

// ================= Layer-1 aggregate, wave per node ===========================
__global__ __launch_bounds__(256) void k_agg1(
    const int* __restrict__ offs, const int* __restrict__ drugA,
    const float* __restrict__ att1s, const __hip_bfloat16* __restrict__ proj1,
    float* __restrict__ dout) {
  const int lane = threadIdx.x & 63, wid = threadIdx.x >> 6;
  const int n = blockIdx.x * 4 + wid;
  if (n >= NNODES) return;
  const int beg = offs[n], end = offs[n + 1];
  float acc0 = 0.f, acc1 = 0.f, acc2 = 0.f, acc3 = 0.f;
  int j = beg;
  for (; j + 3 < end; j += 4) {
#define LD(i)                                                              \
    const int d##i = drugA[j + i];                                         \
    const float a##i = att1s[j + i];                                       \
    const float p##i = bf2f(proj1[(unsigned)(d##i * 64 + lane)]);
    LD(0) LD(1) LD(2) LD(3)
#undef LD
    acc0 = fmaf(p0, a0, acc0);
    acc1 = fmaf(p1, a1, acc1);
    acc2 = fmaf(p2, a2, acc2);
    acc3 = fmaf(p3, a3, acc3);
  }
  for (; j < end; ++j) {
    const int d0 = drugA[j];
    acc0 = fmaf(bf2f(proj1[(unsigned)(d0 * 64 + lane)]), att1s[j], acc0);
  }
  dout[(size_t)n * 64 + lane] += (acc0 + acc1) + (acc2 + acc3);
}

extern "C" void kernel_launch(void* const* d_in, const int* in_sizes, int n_in,
                              void* d_out, int out_size, void* d_ws, size_t ws_size,
                              hipStream_t stream) {
  const float* x = (const float*)d_in[0];
  const int* ei = (const int*)d_in[1];
  const float* W0 = (const float*)d_in[2];
  const float* a10 = (const float*)d_in[3];
  const float* a20 = (const float*)d_in[4];
  const float* a30 = (const float*)d_in[5];
  // d_in[6] = Wskip0: unused (layer-0 skip is identity, F==DIN)
  const float* b0 = (const float*)d_in[7];
  const float* W1 = (const float*)d_in[8];
  const float* a11 = (const float*)d_in[9];
  const float* a21 = (const float*)d_in[10];
  const float* a31 = (const float*)d_in[11];
  const float* Wskip1 = (const float*)d_in[12];
  const float* b1 = (const float*)d_in[13];
  float* out = (float*)d_out;

  // ---- Workspace layout: ~135 MB ----
  __hip_bfloat16* P = (__hip_bfloat16*)d_ws;         // N*256 bf16 (proj0/proj1)
  __hip_bfloat16* out0b = P + (size_t)NNODES * 256;  // N*256 bf16 (h)
  float* s1_0 = (float*)(out0b + (size_t)NNODES * 256);  // N*4 x3
  float* s2_0 = s1_0 + (size_t)NNODES * 4;
  float* s3_0 = s2_0 + (size_t)NNODES * 4;
  float* sums0 = s3_0 + (size_t)NNODES * 4;          // N*4
  float* esx0 = sums0 + (size_t)NNODES * 4;          // 2E*4 (float4/slot)
  int* drugA = (int*)(esx0 + (size_t)2 * NEDGES * 4);  // 2E
  int* otherRole = drugA + 2 * NEDGES;               // 2E
  int* offs = otherRole + 2 * NEDGES;                // N+16
  float* s1_1 = (float*)(offs + NNODES + 16);        // N x3
  float* s2_1 = s1_1 + NNODES;
  float* s3_1 = s2_1 + NNODES;
  float* sums1 = s3_1 + NNODES;                      // N
  __hip_bfloat16* B0swz = (__hip_bfloat16*)(sums1 + NNODES);  // 17408 bf16
  __hip_bfloat16* B1swz = B0swz + 17408;             // 36864 bf16
  // CSR-build int scratch aliases out0b region (dead until k_agg0w):
  int* deg = (int*)out0b;
  int* cursor = deg + NNODES;
  int* bsums = cursor + NNODES;

  __hip_bfloat16* proj0 = P;
  __hip_bfloat16* proj1 = P;   // aliases proj0 (dead after k_agg0w)
  float* es1 = esx0;           // layer-1 att slots (esx0 dead after k_agg0w)

  // ---- weight prep (independent) ----
  k_prep0<<<68, 256, 0, stream>>>(W0, a10, a20, a30, B0swz);
  k_prepw1<<<144, 256, 0, stream>>>(W1, Wskip1, a11, a21, a31, B1swz);

  // ---- Layer-0 projection + scores via MFMA ----
  k_mm0<<<(NNODES + 63) / 64, 256, 0, stream>>>(x, (const short*)B0swz, proj0,
                                                s1_0, s2_0, s3_0);

  // ---- CSR build (records only) ----
  hipMemsetAsync(deg, 0, NNODES * sizeof(int), stream);
  k_deg<<<(2 * NEDGES + 255) / 256, 256, 0, stream>>>(ei, deg);
  k_scan1<<<NB_SCAN, 256, 0, stream>>>(deg, offs, bsums);
  k_scan2<<<1, 512, 0, stream>>>(bsums);
  k_scan3<<<NB_SCAN, 256, 0, stream>>>(offs, bsums, cursor);
  k_fill3<<<(2 * NEDGES + 255) / 256, 256, 0, stream>>>(ei, cursor, drugA,
                                                        otherRole);

  // ---- Layer 0: slot scores+sums -> att -> aggregate ----
  k_sums0x<<<NB_SCAN, 256, 0, stream>>>(offs, drugA, otherRole, s1_0, s2_0,
                                        s3_0, esx0, sums0);
  k_att0<<<NB_SCAN, 256, 0, stream>>>(offs, otherRole, sums0, esx0);
  k_agg0w<<<(NNODES + 3) / 4, 256, 0, stream>>>(offs, drugA, esx0, proj0, x,
                                                b0, out0b);

  // ---- Layer 1: MFMA GEMM (proj+skip+scores) -> slot att -> aggregate ----
  k_mm1<<<(NNODES + 63) / 64, 256, 0, stream>>>(out0b, (const short*)B1swz, b1,
                                                proj1, out, s1_1, s2_1, s3_1);
  k_sums1x<<<NB_SCAN, 256, 0, stream>>>(offs, drugA, otherRole, s1_1, s2_1,
                                        s3_1, es1, sums1);
  k_att1<<<NB_SCAN, 256, 0, stream>>>(offs, otherRole, sums1, es1);
  k_agg1<<<(NNODES + 3) / 4, 256, 0, stream>>>(offs, drugA, es1, proj1, out);
}